// Round 4
// baseline (341.440 us; speedup 1.0000x reference)
//
#include <hip/hip_runtime.h>
#include <hip/hip_bf16.h>

#define NNODES 50000
#define NEDGES 800000
#define HIDDIM 128
#define NGRAPH 64
#define BUCKET 64  // fixed CSR bucket capacity (mean deg 16, P(deg>=64)~2e-18)

typedef __attribute__((ext_vector_type(8))) short short8;
typedef __attribute__((ext_vector_type(4))) float floatx4;
typedef __attribute__((ext_vector_type(4))) unsigned short ushortx4;
typedef __attribute__((ext_vector_type(4))) unsigned int uintx4;

__device__ __forceinline__ float bfbits2f(unsigned short u) {
    return __uint_as_float(((unsigned int)u) << 16);
}
__device__ __forceinline__ unsigned short f2bfbits(float v) {
    __hip_bfloat16 h = __float2bfloat16(v);
    return __builtin_bit_cast(unsigned short, h);
}
__device__ __forceinline__ float bflo(unsigned int w) { return __uint_as_float(w << 16); }
__device__ __forceinline__ float bfhi(unsigned int w) { return __uint_as_float(w & 0xffff0000u); }

// ---------------- runtime dtype detection ----------------
// flags[0]=1: floats stored bf16; 0: fp32.  flags[1]=1: indices int64; 0: int32.
__global__ void k_detect(const unsigned int* __restrict__ xw,
                         const unsigned int* __restrict__ eiw,
                         int* __restrict__ flags) {
    __shared__ int sh_hit, sh_zero;
    int t = threadIdx.x;
    if (t == 0) { sh_hit = 0; sh_zero = 0; }
    __syncthreads();
    if (t < 128) {
        unsigned int w = xw[t * 97 + 5];
        int e = (int)((w >> 7) & 0xFF);
        if (e >= 110 && e <= 140) atomicAdd(&sh_hit, 1);
        if (eiw[1001 + 2 * t] == 0) atomicAdd(&sh_zero, 1);
    }
    __syncthreads();
    if (t == 0) {
        flags[0] = (sh_hit >= 64) ? 1 : 0;
        flags[1] = (sh_zero >= 120) ? 1 : 0;
    }
}

// fused: zero cnt (all blocks) + detect (block 0). CSR path only.
__global__ void k_init(const unsigned int* __restrict__ xw,
                       const unsigned int* __restrict__ eiw,
                       int* __restrict__ flags, int* __restrict__ cnt) {
    __shared__ int sh_hit, sh_zero;
    int t = threadIdx.x;
    int i = blockIdx.x * 256 + t;
    if (i < 50176) cnt[i] = 0;
    if (blockIdx.x != 0) return;
    if (t == 0) { sh_hit = 0; sh_zero = 0; }
    __syncthreads();
    if (t < 128) {
        unsigned int w = xw[t * 97 + 5];
        int e = (int)((w >> 7) & 0xFF);
        if (e >= 110 && e <= 140) atomicAdd(&sh_hit, 1);
        if (eiw[1001 + 2 * t] == 0) atomicAdd(&sh_zero, 1);
    }
    __syncthreads();
    if (t == 0) {
        flags[0] = (sh_hit >= 64) ? 1 : 0;
        flags[1] = (sh_zero >= 120) ? 1 : 0;
    }
}

__device__ __forceinline__ int ld_idx(const int* __restrict__ p, int j, int wide) {
    return wide ? p[2 * j] : p[j];
}

// ---------------- bucket-CSR build: 8 edges/thread ----------
// Last block computes pool bounds (folded k_bounds). Duration invariant to
// 2-vs-8 edges/thread and plain-vs-nt stores (rounds 0/3): bound by per-edge
// atomic+scattered-line pipe. Proper fix = radix partition build (next).
__global__ __launch_bounds__(256) void k_append(const int* __restrict__ ei,
                                                const int* __restrict__ bat,
                                                const int* __restrict__ flags,
                                                int* __restrict__ cnt,
                                                unsigned short* __restrict__ ecol,
                                                int* __restrict__ bounds) {
    if (blockIdx.x == gridDim.x - 1) {
        int g = threadIdx.x;
        if (g > NGRAPH) return;
        int wide = flags[1];
        int lo = 0, hi = NNODES;
        while (lo < hi) {
            int mid = (lo + hi) >> 1;
            if (ld_idx(bat, mid, wide) < g) lo = mid + 1; else hi = mid;
        }
        bounds[g] = lo;
        return;
    }
    int T = blockIdx.x * 256 + threadIdx.x;
    int e0 = T * 8;
    if (e0 >= NEDGES) return;  // NEDGES % 8 == 0, so in-range threads own full groups
    int wide = flags[1];
    int s[8], d[8];
    if (wide) {
        const int4* __restrict__ sp = (const int4*)ei;
        const int4* __restrict__ dp = (const int4*)(ei + 2 * NEDGES);
#pragma unroll
        for (int q = 0; q < 4; ++q) {
            int4 sv = sp[T * 4 + q]; s[2 * q] = sv.x; s[2 * q + 1] = sv.z;
            int4 dv = dp[T * 4 + q]; d[2 * q] = dv.x; d[2 * q + 1] = dv.z;
        }
    } else {
        const int4* __restrict__ sp = (const int4*)ei;
        const int4* __restrict__ dp = (const int4*)(ei + NEDGES);
#pragma unroll
        for (int q = 0; q < 2; ++q) {
            int4 sv = sp[T * 2 + q];
            s[4 * q] = sv.x; s[4 * q + 1] = sv.y; s[4 * q + 2] = sv.z; s[4 * q + 3] = sv.w;
            int4 dv = dp[T * 2 + q];
            d[4 * q] = dv.x; d[4 * q + 1] = dv.y; d[4 * q + 2] = dv.z; d[4 * q + 3] = dv.w;
        }
    }
    int p[8];
#pragma unroll
    for (int q = 0; q < 8; ++q) p[q] = atomicAdd(&cnt[d[q]], 1);
#pragma unroll
    for (int q = 0; q < 8; ++q) {
        if (p[q] < BUCKET) {
            __builtin_nontemporal_store((unsigned short)s[q],
                                        &ecol[(size_t)d[q] * BUCKET + p[q]]);
        }
    }
}

// ---------------- MFMA GEMM: out_bf16[M,128] = (A @ W) * rsqrt(cnt[m]+1) ----------
// a_mode: 0=fp32 A, 1=A follows flags[0], 2=A is bf16 bits.
// Layouts (m89/m120-verified): A m=lane&15,k=quad*8+j ; B k=quad*8+j,n=lane&15 ;
// D row=quad*4+i, col=lane&15.
__global__ __launch_bounds__(256) void k_gemm_mfma(const void* __restrict__ A,
                                                   const void* __restrict__ W,
                                                   const int* __restrict__ flags,
                                                   int a_mode,
                                                   const int* __restrict__ degcnt,
                                                   unsigned short* __restrict__ out,
                                                   int M) {
    __shared__ __align__(16) unsigned short Wl[16 * 128 * 8];   // 32 KB: [kb][n][j]
    __shared__ __align__(16) unsigned short Alds[64 * 17 * 8];  // 17 KB: [m][kb(+pad)][j]
    const int tid = threadIdx.x;
    const int F = flags[0];
    const int abf = (a_mode == 2) ? 1 : (a_mode == 1 ? F : 0);
    const int row0 = blockIdx.x * 64;

    // stage W -> Wl[(kb*128 + n)*8 + kj]
    if (F) {
        const ushort4* __restrict__ Wg = (const ushort4*)W;
#pragma unroll
        for (int it = 0; it < 16; ++it) {
            int idx = it * 256 + tid;
            int k = idx >> 5, n = (idx & 31) * 4;
            ushort4 wv = Wg[idx];
            unsigned short* dst = &Wl[(((k >> 3) * 128) + n) * 8 + (k & 7)];
            dst[0] = wv.x; dst[8] = wv.y; dst[16] = wv.z; dst[24] = wv.w;
        }
    } else {
        const float4* __restrict__ Wg = (const float4*)W;
#pragma unroll
        for (int it = 0; it < 16; ++it) {
            int idx = it * 256 + tid;
            int k = idx >> 5, n = (idx & 31) * 4;
            float4 wv = Wg[idx];
            unsigned short* dst = &Wl[(((k >> 3) * 128) + n) * 8 + (k & 7)];
            dst[0] = f2bfbits(wv.x); dst[8]  = f2bfbits(wv.y);
            dst[16] = f2bfbits(wv.z); dst[24] = f2bfbits(wv.w);
        }
    }
    // stage A rows [row0, row0+64) -> Alds[(m*17 + kb)*8 + kj]
    if (abf) {
#pragma unroll
        for (int it = 0; it < 4; ++it) {
            int idx = it * 256 + tid;          // m=idx>>4, kb=idx&15
            int m = idx >> 4, kb = idx & 15;
            int gr = row0 + m;
            uint4 v = make_uint4(0, 0, 0, 0);
            if (gr < M) v = ((const uint4*)A)[(size_t)gr * 16 + kb];
            *reinterpret_cast<uint4*>(&Alds[(m * 17 + kb) * 8]) = v;
        }
    } else {
#pragma unroll
        for (int it = 0; it < 8; ++it) {
            int idx = it * 256 + tid;          // m=idx>>5, k4=idx&31
            int m = idx >> 5, k4 = idx & 31;
            int k = k4 * 4;
            int gr = row0 + m;
            float4 v = make_float4(0, 0, 0, 0);
            if (gr < M) v = ((const float4*)A)[(size_t)gr * 32 + k4];
            ushort4 u;
            u.x = f2bfbits(v.x); u.y = f2bfbits(v.y);
            u.z = f2bfbits(v.z); u.w = f2bfbits(v.w);
            *reinterpret_cast<ushort4*>(&Alds[(m * 17 + (k >> 3)) * 8 + (k & 7)]) = u;
        }
    }
    __syncthreads();

    const int lane = tid & 63;
    const int wave = tid >> 6;
    const int q = lane >> 4;
    const int c = lane & 15;
    const int mrow = wave * 16 + c;
    floatx4 acc[8] = {};
#pragma unroll
    for (int k0 = 0; k0 < 4; ++k0) {
        int kb = k0 * 4 + q;
        short8 afrag = *reinterpret_cast<const short8*>(&Alds[(mrow * 17 + kb) * 8]);
#pragma unroll
        for (int t = 0; t < 8; ++t) {
            short8 bfrag = *reinterpret_cast<const short8*>(&Wl[(kb * 128 + t * 16 + c) * 8]);
            acc[t] = __builtin_amdgcn_mfma_f32_16x16x32_bf16(afrag, bfrag, acc[t], 0, 0, 0);
        }
    }
#pragma unroll
    for (int i = 0; i < 4; ++i) {
        int gr = row0 + wave * 16 + q * 4 + i;
        if (gr < M) {
            float s = degcnt ? rsqrtf((float)degcnt[gr] + 1.0f) : 1.0f;
#pragma unroll
            for (int t = 0; t < 8; ++t) {
                out[(size_t)gr * 128 + t * 16 + c] = f2bfbits(acc[t][i] * s);
            }
        }
    }
}

// ---------------- FUSED gather+GEMM: out = (relu(gather(tmp16)+b) @ W) * dinv ------
// Block owns 64 destination rows. Phase 1: stage W to LDS + gather rows (bias+relu+
// own-dinv scale) straight into the MFMA A-fragment layout in LDS (16 lanes/node,
// 16 nodes in flight, 4 groups). Phase 2: MFMA with W, prescale output rows by dinv
// for the NEXT gather. Eliminates one 12.8MB write + 12.8MB read per layer boundary;
// MFMA rides under gather latency (gather VALUBusy was 18%).
__global__ __launch_bounds__(256) void k_fused(const int* __restrict__ cnt,
                                               const unsigned short* __restrict__ ecol,
                                               const unsigned short* __restrict__ tmp16,
                                               const void* __restrict__ bias,
                                               const void* __restrict__ W,
                                               const int* __restrict__ flags,
                                               unsigned short* __restrict__ out,
                                               int M) {
    __shared__ __align__(16) unsigned short Wl[16 * 128 * 8];   // 32 KB: [kb][n][j]
    __shared__ __align__(16) unsigned short Alds[64 * 17 * 8];  // 17 KB: [m][kb(+pad)][j]
    const int tid = threadIdx.x;
    const int F = flags[0];
    const int row0 = blockIdx.x * 64;

    // ---- stage W -> Wl (same layout as k_gemm_mfma) ----
    if (F) {
        const ushort4* __restrict__ Wg = (const ushort4*)W;
#pragma unroll
        for (int it = 0; it < 16; ++it) {
            int idx = it * 256 + tid;
            int k = idx >> 5, n = (idx & 31) * 4;
            ushort4 wv = Wg[idx];
            unsigned short* dst = &Wl[(((k >> 3) * 128) + n) * 8 + (k & 7)];
            dst[0] = wv.x; dst[8] = wv.y; dst[16] = wv.z; dst[24] = wv.w;
        }
    } else {
        const float4* __restrict__ Wg = (const float4*)W;
#pragma unroll
        for (int it = 0; it < 16; ++it) {
            int idx = it * 256 + tid;
            int k = idx >> 5, n = (idx & 31) * 4;
            float4 wv = Wg[idx];
            unsigned short* dst = &Wl[(((k >> 3) * 128) + n) * 8 + (k & 7)];
            dst[0] = f2bfbits(wv.x); dst[8]  = f2bfbits(wv.y);
            dst[16] = f2bfbits(wv.z); dst[24] = f2bfbits(wv.w);
        }
    }

    // ---- gather phase: 16 lanes/node, 16 nodes in flight, 4 groups ----
    {
        const uint4* __restrict__ base = reinterpret_cast<const uint4*>(tmp16);
        const int jl = tid & 15;      // 16B chunk = bf16 cols [jl*8, jl*8+8)
        const int nsub = tid >> 4;    // node-in-group
        float b[8];
        if (F) {
            uint4 bb = ((const uint4*)bias)[jl];
            b[0] = bflo(bb.x); b[1] = bfhi(bb.x);
            b[2] = bflo(bb.y); b[3] = bfhi(bb.y);
            b[4] = bflo(bb.z); b[5] = bfhi(bb.z);
            b[6] = bflo(bb.w); b[7] = bfhi(bb.w);
        } else {
            float4 f0 = ((const float4*)bias)[2 * jl];
            float4 f1 = ((const float4*)bias)[2 * jl + 1];
            b[0] = f0.x; b[1] = f0.y; b[2] = f0.z; b[3] = f0.w;
            b[4] = f1.x; b[5] = f1.y; b[6] = f1.z; b[7] = f1.w;
        }
#pragma unroll
        for (int grp = 0; grp < 4; ++grp) {
            int m = grp * 16 + nsub;
            int n = row0 + m;
            float a[8] = {0, 0, 0, 0, 0, 0, 0, 0};
            float dn = 1.0f;
            bool live = (n < M);
            if (live) {
                int degf = cnt[n];
                dn = rsqrtf((float)degf + 1.0f);
                int deg = degf > BUCKET ? BUCKET : degf;
                const unsigned short* __restrict__ bk = &ecol[(size_t)n * BUCKET];
                uint4 u = base[(size_t)n * 16 + jl];  // self-loop (pre-scaled)
                a[0] = bflo(u.x); a[1] = bfhi(u.x);
                a[2] = bflo(u.y); a[3] = bfhi(u.y);
                a[4] = bflo(u.z); a[5] = bfhi(u.z);
                a[6] = bflo(u.w); a[7] = bfhi(u.w);
                int k = 0;
                for (; k + 3 < deg; k += 4) {
                    ushortx4 sv = __builtin_nontemporal_load(
                        reinterpret_cast<const ushortx4*>(&bk[k]));
                    uint4 u0 = base[(size_t)sv[0] * 16 + jl];
                    uint4 u1 = base[(size_t)sv[1] * 16 + jl];
                    uint4 u2 = base[(size_t)sv[2] * 16 + jl];
                    uint4 u3 = base[(size_t)sv[3] * 16 + jl];
                    a[0] += (bflo(u0.x) + bflo(u1.x)) + (bflo(u2.x) + bflo(u3.x));
                    a[1] += (bfhi(u0.x) + bfhi(u1.x)) + (bfhi(u2.x) + bfhi(u3.x));
                    a[2] += (bflo(u0.y) + bflo(u1.y)) + (bflo(u2.y) + bflo(u3.y));
                    a[3] += (bfhi(u0.y) + bfhi(u1.y)) + (bfhi(u2.y) + bfhi(u3.y));
                    a[4] += (bflo(u0.z) + bflo(u1.z)) + (bflo(u2.z) + bflo(u3.z));
                    a[5] += (bfhi(u0.z) + bfhi(u1.z)) + (bfhi(u2.z) + bfhi(u3.z));
                    a[6] += (bflo(u0.w) + bflo(u1.w)) + (bflo(u2.w) + bflo(u3.w));
                    a[7] += (bfhi(u0.w) + bfhi(u1.w)) + (bfhi(u2.w) + bfhi(u3.w));
                }
                for (; k < deg; ++k) {
                    uint4 u0 = base[(size_t)bk[k] * 16 + jl];
                    a[0] += bflo(u0.x); a[1] += bfhi(u0.x);
                    a[2] += bflo(u0.y); a[3] += bfhi(u0.y);
                    a[4] += bflo(u0.z); a[5] += bfhi(u0.z);
                    a[6] += bflo(u0.w); a[7] += bfhi(u0.w);
                }
            }
            unsigned int ow[4];
#pragma unroll
            for (int i2 = 0; i2 < 4; ++i2) {
                float r0 = live ? fmaxf(a[2 * i2]     * dn + b[2 * i2],     0.0f) : 0.0f;
                float r1 = live ? fmaxf(a[2 * i2 + 1] * dn + b[2 * i2 + 1], 0.0f) : 0.0f;
                ow[i2] = (unsigned int)f2bfbits(r0) | ((unsigned int)f2bfbits(r1) << 16);
            }
            *reinterpret_cast<uint4*>(&Alds[(m * 17 + jl) * 8]) =
                make_uint4(ow[0], ow[1], ow[2], ow[3]);
        }
    }
    __syncthreads();

    // ---- MFMA phase (identical to k_gemm_mfma) ----
    const int lane = tid & 63;
    const int wave = tid >> 6;
    const int q = lane >> 4;
    const int c = lane & 15;
    const int mrow = wave * 16 + c;
    floatx4 acc[8] = {};
#pragma unroll
    for (int k0 = 0; k0 < 4; ++k0) {
        int kb = k0 * 4 + q;
        short8 afrag = *reinterpret_cast<const short8*>(&Alds[(mrow * 17 + kb) * 8]);
#pragma unroll
        for (int t = 0; t < 8; ++t) {
            short8 bfrag = *reinterpret_cast<const short8*>(&Wl[(kb * 128 + t * 16 + c) * 8]);
            acc[t] = __builtin_amdgcn_mfma_f32_16x16x32_bf16(afrag, bfrag, acc[t], 0, 0, 0);
        }
    }
#pragma unroll
    for (int i = 0; i < 4; ++i) {
        int gr = row0 + wave * 16 + q * 4 + i;
        if (gr < M) {
            float s = rsqrtf((float)cnt[gr] + 1.0f);  // prescale for next gather
#pragma unroll
            for (int t = 0; t < 8; ++t) {
                out[(size_t)gr * 128 + t * 16 + c] = f2bfbits(acc[t][i] * s);
            }
        }
    }
}

// ---------------- fused gather (bf16 in/out): row-sum + scale + bias + relu --------
// 16 lanes/node, one dwordx4 per lane per neighbor row. deg-bounded loop.
__global__ __launch_bounds__(256) void k_gather(const int* __restrict__ cnt,
                                                const unsigned short* __restrict__ ecol,
                                                const unsigned short* __restrict__ tmp16,
                                                const void* __restrict__ bias,
                                                const int* __restrict__ flags,
                                                unsigned short* __restrict__ outh16) {
    int t = blockIdx.x * 256 + threadIdx.x;
    int n = t >> 4;
    if (n >= NNODES) return;
    int j = t & 15;  // 16B chunk = bf16 columns [j*8, j*8+8)
    int degf = cnt[n];
    float dn = rsqrtf((float)degf + 1.0f);
    int deg = degf > BUCKET ? BUCKET : degf;
    const unsigned short* __restrict__ bk = &ecol[(size_t)n * BUCKET];
    const uint4* __restrict__ base = reinterpret_cast<const uint4*>(tmp16);
    float a[8];
    {
        uint4 u = base[(size_t)n * 16 + j];  // self-loop term (pre-scaled)
        a[0] = bflo(u.x); a[1] = bfhi(u.x);
        a[2] = bflo(u.y); a[3] = bfhi(u.y);
        a[4] = bflo(u.z); a[5] = bfhi(u.z);
        a[6] = bflo(u.w); a[7] = bfhi(u.w);
    }
    int k = 0;
    for (; k + 3 < deg; k += 4) {
        ushortx4 sv = __builtin_nontemporal_load(
            reinterpret_cast<const ushortx4*>(&bk[k]));
        uint4 u0 = base[(size_t)sv[0] * 16 + j];
        uint4 u1 = base[(size_t)sv[1] * 16 + j];
        uint4 u2 = base[(size_t)sv[2] * 16 + j];
        uint4 u3 = base[(size_t)sv[3] * 16 + j];
        a[0] += (bflo(u0.x) + bflo(u1.x)) + (bflo(u2.x) + bflo(u3.x));
        a[1] += (bfhi(u0.x) + bfhi(u1.x)) + (bfhi(u2.x) + bfhi(u3.x));
        a[2] += (bflo(u0.y) + bflo(u1.y)) + (bflo(u2.y) + bflo(u3.y));
        a[3] += (bfhi(u0.y) + bfhi(u1.y)) + (bfhi(u2.y) + bfhi(u3.y));
        a[4] += (bflo(u0.z) + bflo(u1.z)) + (bflo(u2.z) + bflo(u3.z));
        a[5] += (bfhi(u0.z) + bfhi(u1.z)) + (bfhi(u2.z) + bfhi(u3.z));
        a[6] += (bflo(u0.w) + bflo(u1.w)) + (bflo(u2.w) + bflo(u3.w));
        a[7] += (bfhi(u0.w) + bfhi(u1.w)) + (bfhi(u2.w) + bfhi(u3.w));
    }
    for (; k < deg; ++k) {
        uint4 u0 = base[(size_t)bk[k] * 16 + j];
        a[0] += bflo(u0.x); a[1] += bfhi(u0.x);
        a[2] += bflo(u0.y); a[3] += bfhi(u0.y);
        a[4] += bflo(u0.z); a[5] += bfhi(u0.z);
        a[6] += bflo(u0.w); a[7] += bfhi(u0.w);
    }
    float b[8];
    if (flags[0]) {
        uint4 bb = ((const uint4*)bias)[j];
        b[0] = bflo(bb.x); b[1] = bfhi(bb.x);
        b[2] = bflo(bb.y); b[3] = bfhi(bb.y);
        b[4] = bflo(bb.z); b[5] = bfhi(bb.z);
        b[6] = bflo(bb.w); b[7] = bfhi(bb.w);
    } else {
        float4 f0 = ((const float4*)bias)[2 * j];
        float4 f1 = ((const float4*)bias)[2 * j + 1];
        b[0] = f0.x; b[1] = f0.y; b[2] = f0.z; b[3] = f0.w;
        b[4] = f1.x; b[5] = f1.y; b[6] = f1.z; b[7] = f1.w;
    }
    uintx4 ov;
#pragma unroll
    for (int i2 = 0; i2 < 4; ++i2) {
        float r0 = fmaxf(a[2 * i2]     * dn + b[2 * i2],     0.0f);
        float r1 = fmaxf(a[2 * i2 + 1] * dn + b[2 * i2 + 1], 0.0f);
        ov[i2] = (unsigned int)f2bfbits(r0) | ((unsigned int)f2bfbits(r1) << 16);
    }
    __builtin_nontemporal_store(ov,
        reinterpret_cast<uintx4*>(outh16 + (size_t)n * 128 + j * 8));
}

// ---------------- fallback (round-3 proven) atomic-scatter path ----------------
__global__ __launch_bounds__(256) void k_gemm(const void* __restrict__ A,
                                              const void* __restrict__ W,
                                              const int* __restrict__ flags,
                                              int a_uses_flag,
                                              float* __restrict__ out, int M) {
    __shared__ __align__(16) float Al[32 * 128];
    const int tid = threadIdx.x;
    const int F = flags[0];
    const int afmt = a_uses_flag ? F : 0;
    const int row0 = blockIdx.x * 32;
#pragma unroll
    for (int j = 0; j < 16; ++j) {
        int idx = j * 256 + tid;
        int r = idx >> 7, k = idx & 127;
        int gr = row0 + r;
        float v = 0.0f;
        if (gr < M) {
            size_t off = (size_t)gr * 128 + k;
            v = afmt ? bfbits2f(((const unsigned short*)A)[off])
                     : ((const float*)A)[off];
        }
        Al[idx] = v;
    }
    __syncthreads();
    const int tx = tid & 31, ty = tid >> 5;
    const int c0 = tx * 4;
    float acc[4][4] = {};
    if (F) {
        const ushort4* __restrict__ Wg = (const ushort4*)W;
#pragma unroll 4
        for (int k = 0; k < 128; ++k) {
            ushort4 wv = Wg[k * 32 + tx];
            float w0 = bfbits2f(wv.x), w1 = bfbits2f(wv.y);
            float w2 = bfbits2f(wv.z), w3 = bfbits2f(wv.w);
#pragma unroll
            for (int i = 0; i < 4; ++i) {
                float a = Al[(ty + i * 8) * 128 + k];
                acc[i][0] = fmaf(a, w0, acc[i][0]);
                acc[i][1] = fmaf(a, w1, acc[i][1]);
                acc[i][2] = fmaf(a, w2, acc[i][2]);
                acc[i][3] = fmaf(a, w3, acc[i][3]);
            }
        }
    } else {
        const float4* __restrict__ Wg = (const float4*)W;
#pragma unroll 4
        for (int k = 0; k < 128; ++k) {
            float4 wv = Wg[k * 32 + tx];
#pragma unroll
            for (int i = 0; i < 4; ++i) {
                float a = Al[(ty + i * 8) * 128 + k];
                acc[i][0] = fmaf(a, wv.x, acc[i][0]);
                acc[i][1] = fmaf(a, wv.y, acc[i][1]);
                acc[i][2] = fmaf(a, wv.z, acc[i][2]);
                acc[i][3] = fmaf(a, wv.w, acc[i][3]);
            }
        }
    }
#pragma unroll
    for (int i = 0; i < 4; ++i) {
        int gr = row0 + ty + i * 8;
        if (gr < M) {
            *reinterpret_cast<float4*>(&out[(size_t)gr * 128 + c0]) =
                make_float4(acc[i][0], acc[i][1], acc[i][2], acc[i][3]);
        }
    }
}
__global__ void k_deg_init(float* __restrict__ deg) {
    int i = blockIdx.x * 256 + threadIdx.x;
    if (i < NNODES) deg[i] = 1.0f;
}
__global__ void k_deg_edges(const int* __restrict__ ei, const int* __restrict__ flags,
                            float* __restrict__ deg) {
    int e = blockIdx.x * 256 + threadIdx.x;
    if (e < NEDGES) unsafeAtomicAdd(&deg[ld_idx(ei, NEDGES + e, flags[1])], 1.0f);
}
__global__ void k_rsqrt(float* __restrict__ deg) {
    int i = blockIdx.x * 256 + threadIdx.x;
    if (i < NNODES) deg[i] = 1.0f / sqrtf(deg[i]);
}
__global__ void k_selfloop(const float* __restrict__ tmp, const float* __restrict__ dinv,
                           float* __restrict__ agg) {
    int t = blockIdx.x * 256 + threadIdx.x;
    if (t >= NNODES * 32) return;
    int n = t >> 5, j = t & 31;
    float s = dinv[n]; s = s * s;
    float4 v = *reinterpret_cast<const float4*>(&tmp[(size_t)n * 128 + j * 4]);
    v.x *= s; v.y *= s; v.z *= s; v.w *= s;
    *reinterpret_cast<float4*>(&agg[(size_t)n * 128 + j * 4]) = v;
}
__global__ __launch_bounds__(256) void k_scatter(const int* __restrict__ ei,
                                                 const int* __restrict__ flags,
                                                 const float* __restrict__ dinv,
                                                 const float* __restrict__ tmp,
                                                 float* __restrict__ agg) {
    int t = blockIdx.x * 256 + threadIdx.x;
    int e = t >> 5;
    if (e >= NEDGES) return;
    int j = t & 31;
    int wide = flags[1];
    int s = ld_idx(ei, e, wide);
    int d = ld_idx(ei, NEDGES + e, wide);
    float w = dinv[s] * dinv[d];
    const float4 v = *reinterpret_cast<const float4*>(&tmp[(size_t)s * 128 + j * 4]);
    float* p = &agg[(size_t)d * 128 + j * 4];
    unsafeAtomicAdd(p + 0, v.x * w);
    unsafeAtomicAdd(p + 1, v.y * w);
    unsafeAtomicAdd(p + 2, v.z * w);
    unsafeAtomicAdd(p + 3, v.w * w);
}
__global__ void k_bias_relu(float* __restrict__ h, const void* __restrict__ b,
                            const int* __restrict__ flags) {
    int t = blockIdx.x * 256 + threadIdx.x;
    if (t >= NNODES * 32) return;
    int j = t & 31;
    float b0, b1, b2, b3;
    if (flags[0]) {
        const unsigned short* bb = (const unsigned short*)b;
        b0 = bfbits2f(bb[j * 4 + 0]); b1 = bfbits2f(bb[j * 4 + 1]);
        b2 = bfbits2f(bb[j * 4 + 2]); b3 = bfbits2f(bb[j * 4 + 3]);
    } else {
        const float* bb = (const float*)b;
        b0 = bb[j * 4 + 0]; b1 = bb[j * 4 + 1]; b2 = bb[j * 4 + 2]; b3 = bb[j * 4 + 3];
    }
    float4 v = *reinterpret_cast<float4*>(&h[(size_t)t * 4]);
    v.x = fmaxf(v.x + b0, 0.0f);
    v.y = fmaxf(v.y + b1, 0.0f);
    v.z = fmaxf(v.z + b2, 0.0f);
    v.w = fmaxf(v.w + b3, 0.0f);
    *reinterpret_cast<float4*>(&h[(size_t)t * 4]) = v;
}

// ---------------- pooling ----------------
__global__ void k_bounds(const int* __restrict__ batch, const int* __restrict__ flags,
                         int* __restrict__ bounds) {
    int g = threadIdx.x;
    if (g > NGRAPH) return;
    int wide = flags[1];
    int lo = 0, hi = NNODES;
    while (lo < hi) {
        int mid = (lo + hi) >> 1;
        if (ld_idx(batch, mid, wide) < g) lo = mid + 1; else hi = mid;
    }
    bounds[g] = lo;
}

// stage 1: 256 blocks = 4 segments x 64 graphs; bf16 h input; fp32 partials.
__global__ __launch_bounds__(256) void k_pool_part(const unsigned short* __restrict__ h16,
                                                   const int* __restrict__ bounds,
                                                   float* __restrict__ part) {
    __shared__ float sh[256 * 4];
    int g = blockIdx.x >> 2, seg = blockIdx.x & 3;
    int t = threadIdx.x;
    int c4 = t & 31, sub = t >> 5;  // sub in [0,8)
    int beg = bounds[g], end = bounds[g + 1];
    const ushort4* __restrict__ base = (const ushort4*)h16;
    float ax = 0, ay = 0, az = 0, aw = 0;
    for (int r = beg + seg * 8 + sub; r < end; r += 32) {
        ushort4 u = base[(size_t)r * 32 + c4];
        ax += bfbits2f(u.x); ay += bfbits2f(u.y);
        az += bfbits2f(u.z); aw += bfbits2f(u.w);
    }
    sh[t * 4 + 0] = ax; sh[t * 4 + 1] = ay; sh[t * 4 + 2] = az; sh[t * 4 + 3] = aw;
    __syncthreads();
    if (t < 32) {
        float4 r = make_float4(0, 0, 0, 0);
#pragma unroll
        for (int s = 0; s < 8; ++s) {
            r.x += sh[(s * 32 + t) * 4 + 0];
            r.y += sh[(s * 32 + t) * 4 + 1];
            r.z += sh[(s * 32 + t) * 4 + 2];
            r.w += sh[(s * 32 + t) * 4 + 3];
        }
        *reinterpret_cast<float4*>(&part[((size_t)(g * 4 + seg)) * 128 + t * 4]) = r;
    }
}

__global__ void k_pool_final(const float* __restrict__ part, const int* __restrict__ bounds,
                             const int* __restrict__ flags, void* __restrict__ out) {
    int i = blockIdx.x * 256 + threadIdx.x;
    if (i >= NGRAPH * 128) return;
    int g = i >> 7, col = i & 127;
    float s = part[(g * 4 + 0) * 128 + col] + part[(g * 4 + 1) * 128 + col] +
              part[(g * 4 + 2) * 128 + col] + part[(g * 4 + 3) * 128 + col];
    float c = (float)(bounds[g + 1] - bounds[g]);
    float r = s / fmaxf(c, 1.0f);
    if (flags[0]) ((__hip_bfloat16*)out)[i] = __float2bfloat16(r);
    else          ((float*)out)[i] = r;
}

// fallback pool (fp32 h)
__global__ __launch_bounds__(1024) void k_pool2(const float* __restrict__ h,
                                                const int* __restrict__ bounds,
                                                const int* __restrict__ flags,
                                                void* __restrict__ out) {
    __shared__ float sh[1024];
    int g = blockIdx.x;
    int t = threadIdx.x;
    int beg = bounds[g], end = bounds[g + 1];
    int col = t & 127, seg = t >> 7;
    float acc = 0.0f;
    for (int r = beg + seg; r < end; r += 8)
        acc += h[(size_t)r * 128 + col];
    sh[t] = acc;
    __syncthreads();
    if (t < 128) {
        float total = 0.0f;
#pragma unroll
        for (int i = 0; i < 8; ++i) total += sh[t + 128 * i];
        float c = (float)(end - beg);
        float r = total / fmaxf(c, 1.0f);
        if (flags[0]) ((__hip_bfloat16*)out)[g * 128 + t] = __float2bfloat16(r);
        else          ((float*)out)[g * 128 + t] = r;
    }
}

extern "C" void kernel_launch(void* const* d_in, const int* in_sizes, int n_in,
                              void* d_out, int out_size, void* d_ws, size_t ws_size,
                              hipStream_t stream) {
    const void* x  = d_in[0];
    const int* ei  = (const int*)d_in[1];
    const int* bat = (const int*)d_in[2];
    const void* W0 = d_in[3];
    const void* b0 = d_in[4];
    const void* W1 = d_in[5];
    const void* b1 = d_in[6];
    const void* W2 = d_in[7];
    const void* b2 = d_in[8];

    // Workspace: flags | dinv | hA-region(6.4M f) | hB-region(6.4M f) | bounds | cnt | part
    // CSR path overlays: hA16 = first half of hA-region; ecol(ushort, 6.4MB) in second half;
    // hB16 = first half of hB-region.
    float* ws = (float*)d_ws;
    size_t off = 0;
    int*   flags  = (int*)ws;           off += 16;
    float* dinv   = ws + off;           off += 50176;
    float* hA     = ws + off;           off += (size_t)NNODES * 128;
    float* hB     = ws + off;           off += (size_t)NNODES * 128;
    int*   bounds = (int*)(ws + off);   off += 80;
    int*   cnt    = (int*)(ws + off);   off += 50304;
    float* part   = ws + off;           off += NGRAPH * 4 * 128 + 64;
    const size_t needed = off * 4;
    unsigned short* hA16 = (unsigned short*)hA;
    unsigned short* hB16 = (unsigned short*)hB;
    unsigned short* ecol = (unsigned short*)(hA + (size_t)NNODES * 64);  // 3.2M ushorts

    const int bN  = (NNODES + 255) / 256;       // 196
    const int bE  = (NEDGES + 255) / 256;       // 3125
    const int bNF = (NNODES * 32) / 256;        // 6250
    const int bEF = (NEDGES * 32) / 256;        // 100000
    const int bA8 = (NEDGES / 8 + 255) / 256;   // 391 (append, 8 edges/thread)
    const int bGT = (NNODES * 16) / 256;        // 3125 (gather, 16 lanes/node)
    const int bG  = (NNODES + 31) / 32;         // 1563 (vector gemm)
    const int bG2 = (NNODES + 63) / 64;         // 782  (mfma gemm / fused)
    dim3 blk(256);

    const bool use_csr = (ws_size >= needed);

    if (use_csr) {
        // init (zero cnt + detect) -> append (+bounds in last block)
        hipLaunchKernelGGL(k_init, dim3(bN), blk, 0, stream,
                           (const unsigned int*)x, (const unsigned int*)ei, flags, cnt);
        hipLaunchKernelGGL(k_append, dim3(bA8 + 1), blk, 0, stream,
                           ei, bat, flags, cnt, ecol, bounds);

        // layer 0 GEMM, then fused (gather+bias+relu+GEMM) x2, then final gather
        hipLaunchKernelGGL(k_gemm_mfma, dim3(bG2), blk, 0, stream, x, W0, flags, 1, cnt, hA16, NNODES);
        hipLaunchKernelGGL(k_fused, dim3(bG2), blk, 0, stream, cnt, ecol, hA16, b0, W1, flags, hB16, NNODES);
        hipLaunchKernelGGL(k_fused, dim3(bG2), blk, 0, stream, cnt, ecol, hB16, b1, W2, flags, hA16, NNODES);
        hipLaunchKernelGGL(k_gather, dim3(bGT), blk, 0, stream, cnt, ecol, hA16, b2, flags, hB16);

        // pool: 2-stage reduce (bounds already computed in k_append)
        hipLaunchKernelGGL(k_pool_part, dim3(NGRAPH * 4), blk, 0, stream, hB16, bounds, part);
        hipLaunchKernelGGL(k_pool_final, dim3(32), blk, 0, stream, part, bounds, flags, d_out);
    } else {
        // fallback: round-3 proven atomic path (fp32 everywhere)
        hipLaunchKernelGGL(k_detect, dim3(1), blk, 0, stream,
                           (const unsigned int*)x, (const unsigned int*)ei, flags);
        hipLaunchKernelGGL(k_deg_init, dim3(bN), blk, 0, stream, dinv);
        hipLaunchKernelGGL(k_deg_edges, dim3(bE), blk, 0, stream, ei, flags, dinv);
        hipLaunchKernelGGL(k_rsqrt, dim3(bN), blk, 0, stream, dinv);

        hipLaunchKernelGGL(k_gemm, dim3(bG), blk, 0, stream, x, W0, flags, 1, hA, NNODES);
        hipLaunchKernelGGL(k_selfloop, dim3(bNF), blk, 0, stream, hA, dinv, hB);
        hipLaunchKernelGGL(k_scatter, dim3(bEF), blk, 0, stream, ei, flags, dinv, hA, hB);
        hipLaunchKernelGGL(k_bias_relu, dim3(bNF), blk, 0, stream, hB, b0, flags);

        hipLaunchKernelGGL(k_gemm, dim3(bG), blk, 0, stream, hB, W1, flags, 0, hA, NNODES);
        hipLaunchKernelGGL(k_selfloop, dim3(bNF), blk, 0, stream, hA, dinv, hB);
        hipLaunchKernelGGL(k_scatter, dim3(bEF), blk, 0, stream, ei, flags, dinv, hA, hB);
        hipLaunchKernelGGL(k_bias_relu, dim3(bNF), blk, 0, stream, hB, b1, flags);

        hipLaunchKernelGGL(k_gemm, dim3(bG), blk, 0, stream, hB, W2, flags, 0, hA, NNODES);
        hipLaunchKernelGGL(k_selfloop, dim3(bNF), blk, 0, stream, hA, dinv, hB);
        hipLaunchKernelGGL(k_scatter, dim3(bEF), blk, 0, stream, ei, flags, dinv, hA, hB);
        hipLaunchKernelGGL(k_bias_relu, dim3(bNF), blk, 0, stream, hB, b2, flags);

        hipLaunchKernelGGL(k_bounds, dim3(1), dim3(128), 0, stream, bat, flags, bounds);
        hipLaunchKernelGGL(k_pool2, dim3(NGRAPH), dim3(1024), 0, stream, hB, bounds, flags, d_out);
    }
}

// Round 6
// 320.192 us; speedup vs baseline: 1.0664x; 1.0664x over previous
//
#include <hip/hip_runtime.h>
#include <hip/hip_bf16.h>

#define NNODES 50000
#define NEDGES 800000
#define HIDDIM 128
#define NGRAPH 64
#define BUCKET 64  // fixed CSR bucket capacity (mean deg 16, P(deg>=64)~2e-18)

typedef __attribute__((ext_vector_type(8))) short short8;
typedef __attribute__((ext_vector_type(4))) float floatx4;
typedef __attribute__((ext_vector_type(4))) unsigned int uintx4;

__device__ __forceinline__ float bfbits2f(unsigned short u) {
    return __uint_as_float(((unsigned int)u) << 16);
}
__device__ __forceinline__ unsigned short f2bfbits(float v) {
    __hip_bfloat16 h = __float2bfloat16(v);
    return __builtin_bit_cast(unsigned short, h);
}
__device__ __forceinline__ float bflo(unsigned int w) { return __uint_as_float(w << 16); }
__device__ __forceinline__ float bfhi(unsigned int w) { return __uint_as_float(w & 0xffff0000u); }

// weighted / plain row accumulate into a[8] (inline fns: macro version hit the
// r.w-member vs w-param token-substitution bug in round 5)
__device__ __forceinline__ void acc8w(float* __restrict__ a, uint4 r, float wt) {
    a[0] = fmaf(wt, bflo(r.x), a[0]); a[1] = fmaf(wt, bfhi(r.x), a[1]);
    a[2] = fmaf(wt, bflo(r.y), a[2]); a[3] = fmaf(wt, bfhi(r.y), a[3]);
    a[4] = fmaf(wt, bflo(r.z), a[4]); a[5] = fmaf(wt, bfhi(r.z), a[5]);
    a[6] = fmaf(wt, bflo(r.w), a[6]); a[7] = fmaf(wt, bfhi(r.w), a[7]);
}
__device__ __forceinline__ void acc8p(float* __restrict__ a, uint4 r) {
    a[0] += bflo(r.x); a[1] += bfhi(r.x);
    a[2] += bflo(r.y); a[3] += bfhi(r.y);
    a[4] += bflo(r.z); a[5] += bfhi(r.z);
    a[6] += bflo(r.w); a[7] += bfhi(r.w);
}

// ---------------- runtime dtype detection ----------------
// flags[0]=1: floats stored bf16; 0: fp32.  flags[1]=1: indices int64; 0: int32.
__global__ void k_detect(const unsigned int* __restrict__ xw,
                         const unsigned int* __restrict__ eiw,
                         int* __restrict__ flags) {
    __shared__ int sh_hit, sh_zero;
    int t = threadIdx.x;
    if (t == 0) { sh_hit = 0; sh_zero = 0; }
    __syncthreads();
    if (t < 128) {
        unsigned int w = xw[t * 97 + 5];
        int e = (int)((w >> 7) & 0xFF);
        if (e >= 110 && e <= 140) atomicAdd(&sh_hit, 1);
        if (eiw[1001 + 2 * t] == 0) atomicAdd(&sh_zero, 1);
    }
    __syncthreads();
    if (t == 0) {
        flags[0] = (sh_hit >= 64) ? 1 : 0;
        flags[1] = (sh_zero >= 120) ? 1 : 0;
    }
}

// fused: zero cnt (all blocks) + detect (block 0). CSR path only.
__global__ void k_init(const unsigned int* __restrict__ xw,
                       const unsigned int* __restrict__ eiw,
                       int* __restrict__ flags, int* __restrict__ cnt) {
    __shared__ int sh_hit, sh_zero;
    int t = threadIdx.x;
    int i = blockIdx.x * 256 + t;
    if (i < 50176) cnt[i] = 0;
    if (blockIdx.x != 0) return;
    if (t == 0) { sh_hit = 0; sh_zero = 0; }
    __syncthreads();
    if (t < 128) {
        unsigned int w = xw[t * 97 + 5];
        int e = (int)((w >> 7) & 0xFF);
        if (e >= 110 && e <= 140) atomicAdd(&sh_hit, 1);
        if (eiw[1001 + 2 * t] == 0) atomicAdd(&sh_zero, 1);
    }
    __syncthreads();
    if (t == 0) {
        flags[0] = (sh_hit >= 64) ? 1 : 0;
        flags[1] = (sh_zero >= 120) ? 1 : 0;
    }
}

__device__ __forceinline__ int ld_idx(const int* __restrict__ p, int j, int wide) {
    return wide ? p[2 * j] : p[j];
}

// ---------------- MERGED: CSR append (blocks 0..390) + bounds (391) + gemm0 (392+) --
// Append is atomic-pipe-bound (rounds 0/3: duration invariant to MLP/occupancy/nt);
// gemm0 has no dependency on it once the dinv prescale is deferred to gather-1.
// Co-resident blocks overlap the two phases -> gemm0's ~12us leaves the serial chain.
// gemm0 writes UNSCALED A@W0; gather-1 applies rsqrt(cnt+1) weights explicitly.
__global__ __launch_bounds__(256) void k_g0a(const int* __restrict__ ei,
                                             const int* __restrict__ bat,
                                             const int* __restrict__ flags,
                                             int* __restrict__ cnt,
                                             unsigned short* __restrict__ ecol,
                                             int* __restrict__ bounds,
                                             const void* __restrict__ A,
                                             const void* __restrict__ W,
                                             unsigned short* __restrict__ out,
                                             int M) {
    __shared__ __align__(16) unsigned short Wl[16 * 128 * 8];   // 32 KB: [kb][n][j]
    __shared__ __align__(16) unsigned short Alds[64 * 17 * 8];  // 17 KB: [m][kb(+pad)][j]
    const int tid = threadIdx.x;
    const int F = flags[0];

    if (blockIdx.x < 392) {
        if (blockIdx.x == 391) {  // pool bounds (binary search per graph)
            int g = tid;
            if (g > NGRAPH) return;
            int wide = flags[1];
            int lo = 0, hi = NNODES;
            while (lo < hi) {
                int mid = (lo + hi) >> 1;
                if (ld_idx(bat, mid, wide) < g) lo = mid + 1; else hi = mid;
            }
            bounds[g] = lo;
            return;
        }
        // ---- append: 8 edges/thread ----
        int T = blockIdx.x * 256 + tid;
        int e0 = T * 8;
        if (e0 >= NEDGES) return;
        int wide = flags[1];
        int s[8], d[8];
        if (wide) {
            const int4* __restrict__ sp = (const int4*)ei;
            const int4* __restrict__ dp = (const int4*)(ei + 2 * NEDGES);
#pragma unroll
            for (int q = 0; q < 4; ++q) {
                int4 sv = sp[T * 4 + q]; s[2 * q] = sv.x; s[2 * q + 1] = sv.z;
                int4 dv = dp[T * 4 + q]; d[2 * q] = dv.x; d[2 * q + 1] = dv.z;
            }
        } else {
            const int4* __restrict__ sp = (const int4*)ei;
            const int4* __restrict__ dp = (const int4*)(ei + NEDGES);
#pragma unroll
            for (int q = 0; q < 2; ++q) {
                int4 sv = sp[T * 2 + q];
                s[4 * q] = sv.x; s[4 * q + 1] = sv.y; s[4 * q + 2] = sv.z; s[4 * q + 3] = sv.w;
                int4 dv = dp[T * 2 + q];
                d[4 * q] = dv.x; d[4 * q + 1] = dv.y; d[4 * q + 2] = dv.z; d[4 * q + 3] = dv.w;
            }
        }
        int p[8];
#pragma unroll
        for (int q = 0; q < 8; ++q) p[q] = atomicAdd(&cnt[d[q]], 1);
#pragma unroll
        for (int q = 0; q < 8; ++q) {
            if (p[q] < BUCKET) {
                __builtin_nontemporal_store((unsigned short)s[q],
                                            &ecol[(size_t)d[q] * BUCKET + p[q]]);
            }
        }
        return;
    }

    // ---- gemm0: out = A @ W (bf16 out, NO prescale). A dtype follows flags[0]. ----
    const int row0 = (blockIdx.x - 392) * 64;
    if (F) {
        const ushort4* __restrict__ Wg = (const ushort4*)W;
#pragma unroll
        for (int it = 0; it < 16; ++it) {
            int idx = it * 256 + tid;
            int k = idx >> 5, n = (idx & 31) * 4;
            ushort4 wv = Wg[idx];
            unsigned short* dst = &Wl[(((k >> 3) * 128) + n) * 8 + (k & 7)];
            dst[0] = wv.x; dst[8] = wv.y; dst[16] = wv.z; dst[24] = wv.w;
        }
    } else {
        const float4* __restrict__ Wg = (const float4*)W;
#pragma unroll
        for (int it = 0; it < 16; ++it) {
            int idx = it * 256 + tid;
            int k = idx >> 5, n = (idx & 31) * 4;
            float4 wv = Wg[idx];
            unsigned short* dst = &Wl[(((k >> 3) * 128) + n) * 8 + (k & 7)];
            dst[0] = f2bfbits(wv.x); dst[8]  = f2bfbits(wv.y);
            dst[16] = f2bfbits(wv.z); dst[24] = f2bfbits(wv.w);
        }
    }
    if (F) {
#pragma unroll
        for (int it = 0; it < 4; ++it) {
            int idx = it * 256 + tid;          // m=idx>>4, kb=idx&15
            int m = idx >> 4, kb = idx & 15;
            int gr = row0 + m;
            uint4 v = make_uint4(0, 0, 0, 0);
            if (gr < M) v = ((const uint4*)A)[(size_t)gr * 16 + kb];
            *reinterpret_cast<uint4*>(&Alds[(m * 17 + kb) * 8]) = v;
        }
    } else {
#pragma unroll
        for (int it = 0; it < 8; ++it) {
            int idx = it * 256 + tid;          // m=idx>>5, k4=idx&31
            int m = idx >> 5, k4 = idx & 31;
            int k = k4 * 4;
            int gr = row0 + m;
            float4 v = make_float4(0, 0, 0, 0);
            if (gr < M) v = ((const float4*)A)[(size_t)gr * 32 + k4];
            ushort4 u;
            u.x = f2bfbits(v.x); u.y = f2bfbits(v.y);
            u.z = f2bfbits(v.z); u.w = f2bfbits(v.w);
            *reinterpret_cast<ushort4*>(&Alds[(m * 17 + (k >> 3)) * 8 + (k & 7)]) = u;
        }
    }
    __syncthreads();

    const int lane = tid & 63;
    const int wave = tid >> 6;
    const int q = lane >> 4;
    const int c = lane & 15;
    const int mrow = wave * 16 + c;
    floatx4 acc[8] = {};
#pragma unroll
    for (int k0 = 0; k0 < 4; ++k0) {
        int kb = k0 * 4 + q;
        short8 afrag = *reinterpret_cast<const short8*>(&Alds[(mrow * 17 + kb) * 8]);
#pragma unroll
        for (int t = 0; t < 8; ++t) {
            short8 bfrag = *reinterpret_cast<const short8*>(&Wl[(kb * 128 + t * 16 + c) * 8]);
            acc[t] = __builtin_amdgcn_mfma_f32_16x16x32_bf16(afrag, bfrag, acc[t], 0, 0, 0);
        }
    }
#pragma unroll
    for (int i = 0; i < 4; ++i) {
        int gr = row0 + wave * 16 + q * 4 + i;
        if (gr < M) {
#pragma unroll
            for (int t = 0; t < 8; ++t) {
                out[(size_t)gr * 128 + t * 16 + c] = f2bfbits(acc[t][i]);
            }
        }
    }
}

// ---------------- MFMA GEMM: out_bf16[M,128] = (A @ W) * rsqrt(cnt[m]+1) ----------
// a_mode: 0=fp32 A, 1=A follows flags[0], 2=A is bf16 bits.
__global__ __launch_bounds__(256) void k_gemm_mfma(const void* __restrict__ A,
                                                   const void* __restrict__ W,
                                                   const int* __restrict__ flags,
                                                   int a_mode,
                                                   const int* __restrict__ degcnt,
                                                   unsigned short* __restrict__ out,
                                                   int M) {
    __shared__ __align__(16) unsigned short Wl[16 * 128 * 8];   // 32 KB: [kb][n][j]
    __shared__ __align__(16) unsigned short Alds[64 * 17 * 8];  // 17 KB: [m][kb(+pad)][j]
    const int tid = threadIdx.x;
    const int F = flags[0];
    const int abf = (a_mode == 2) ? 1 : (a_mode == 1 ? F : 0);
    const int row0 = blockIdx.x * 64;

    if (F) {
        const ushort4* __restrict__ Wg = (const ushort4*)W;
#pragma unroll
        for (int it = 0; it < 16; ++it) {
            int idx = it * 256 + tid;
            int k = idx >> 5, n = (idx & 31) * 4;
            ushort4 wv = Wg[idx];
            unsigned short* dst = &Wl[(((k >> 3) * 128) + n) * 8 + (k & 7)];
            dst[0] = wv.x; dst[8] = wv.y; dst[16] = wv.z; dst[24] = wv.w;
        }
    } else {
        const float4* __restrict__ Wg = (const float4*)W;
#pragma unroll
        for (int it = 0; it < 16; ++it) {
            int idx = it * 256 + tid;
            int k = idx >> 5, n = (idx & 31) * 4;
            float4 wv = Wg[idx];
            unsigned short* dst = &Wl[(((k >> 3) * 128) + n) * 8 + (k & 7)];
            dst[0] = f2bfbits(wv.x); dst[8]  = f2bfbits(wv.y);
            dst[16] = f2bfbits(wv.z); dst[24] = f2bfbits(wv.w);
        }
    }
    if (abf) {
#pragma unroll
        for (int it = 0; it < 4; ++it) {
            int idx = it * 256 + tid;          // m=idx>>4, kb=idx&15
            int m = idx >> 4, kb = idx & 15;
            int gr = row0 + m;
            uint4 v = make_uint4(0, 0, 0, 0);
            if (gr < M) v = ((const uint4*)A)[(size_t)gr * 16 + kb];
            *reinterpret_cast<uint4*>(&Alds[(m * 17 + kb) * 8]) = v;
        }
    } else {
#pragma unroll
        for (int it = 0; it < 8; ++it) {
            int idx = it * 256 + tid;          // m=idx>>5, k4=idx&31
            int m = idx >> 5, k4 = idx & 31;
            int k = k4 * 4;
            int gr = row0 + m;
            float4 v = make_float4(0, 0, 0, 0);
            if (gr < M) v = ((const float4*)A)[(size_t)gr * 32 + k4];
            ushort4 u;
            u.x = f2bfbits(v.x); u.y = f2bfbits(v.y);
            u.z = f2bfbits(v.z); u.w = f2bfbits(v.w);
            *reinterpret_cast<ushort4*>(&Alds[(m * 17 + (k >> 3)) * 8 + (k & 7)]) = u;
        }
    }
    __syncthreads();

    const int lane = tid & 63;
    const int wave = tid >> 6;
    const int q = lane >> 4;
    const int c = lane & 15;
    const int mrow = wave * 16 + c;
    floatx4 acc[8] = {};
#pragma unroll
    for (int k0 = 0; k0 < 4; ++k0) {
        int kb = k0 * 4 + q;
        short8 afrag = *reinterpret_cast<const short8*>(&Alds[(mrow * 17 + kb) * 8]);
#pragma unroll
        for (int t = 0; t < 8; ++t) {
            short8 bfrag = *reinterpret_cast<const short8*>(&Wl[(kb * 128 + t * 16 + c) * 8]);
            acc[t] = __builtin_amdgcn_mfma_f32_16x16x32_bf16(afrag, bfrag, acc[t], 0, 0, 0);
        }
    }
#pragma unroll
    for (int i = 0; i < 4; ++i) {
        int gr = row0 + wave * 16 + q * 4 + i;
        if (gr < M) {
            float s = degcnt ? rsqrtf((float)degcnt[gr] + 1.0f) : 1.0f;
#pragma unroll
            for (int t = 0; t < 8; ++t) {
                out[(size_t)gr * 128 + t * 16 + c] = f2bfbits(acc[t][i] * s);
            }
        }
    }
}

// ---------------- fused gather (bf16 in/out): row-sum + scale + bias + relu --------
// 16 lanes/node. 8-wide deg loop: one 16B broadcast bucket word = 8 srcs, 8
// independent dwordx4 row loads in flight per lane (latency-MLP experiment).
// scl==null: rows pre-scaled by dinv (layers 2,3). scl!=null: rows unscaled,
// weight each by rsqrt(scl[src]+1) (layer 1, fed by the unscaled merged gemm0).
__global__ __launch_bounds__(256) void k_gather(const int* __restrict__ cnt,
                                                const unsigned short* __restrict__ ecol,
                                                const unsigned short* __restrict__ tmp16,
                                                const void* __restrict__ bias,
                                                const int* __restrict__ flags,
                                                const int* __restrict__ scl,
                                                unsigned short* __restrict__ outh16) {
    int t = blockIdx.x * 256 + threadIdx.x;
    int n = t >> 4;
    if (n >= NNODES) return;
    int j = t & 15;  // 16B chunk = bf16 columns [j*8, j*8+8)
    int degf = cnt[n];
    float dn = rsqrtf((float)degf + 1.0f);
    int deg = degf > BUCKET ? BUCKET : degf;
    const unsigned short* __restrict__ bk = &ecol[(size_t)n * BUCKET];
    const uint4* __restrict__ base = reinterpret_cast<const uint4*>(tmp16);
    float a[8];
    {
        uint4 u = base[(size_t)n * 16 + j];  // self-loop term
        float w0 = scl ? dn : 1.0f;
        a[0] = w0 * bflo(u.x); a[1] = w0 * bfhi(u.x);
        a[2] = w0 * bflo(u.y); a[3] = w0 * bfhi(u.y);
        a[4] = w0 * bflo(u.z); a[5] = w0 * bfhi(u.z);
        a[6] = w0 * bflo(u.w); a[7] = w0 * bfhi(u.w);
    }
    int k = 0;
    if (scl) {
        for (; k + 7 < deg; k += 8) {
            uint4 bw = *reinterpret_cast<const uint4*>(&bk[k]);
            int s0 = bw.x & 0xffff, s1 = bw.x >> 16;
            int s2 = bw.y & 0xffff, s3 = bw.y >> 16;
            int s4 = bw.z & 0xffff, s5 = bw.z >> 16;
            int s6 = bw.w & 0xffff, s7 = bw.w >> 16;
            uint4 r0 = base[(size_t)s0 * 16 + j];
            uint4 r1 = base[(size_t)s1 * 16 + j];
            uint4 r2 = base[(size_t)s2 * 16 + j];
            uint4 r3 = base[(size_t)s3 * 16 + j];
            uint4 r4 = base[(size_t)s4 * 16 + j];
            uint4 r5 = base[(size_t)s5 * 16 + j];
            uint4 r6 = base[(size_t)s6 * 16 + j];
            uint4 r7 = base[(size_t)s7 * 16 + j];
            acc8w(a, r0, rsqrtf((float)scl[s0] + 1.0f));
            acc8w(a, r1, rsqrtf((float)scl[s1] + 1.0f));
            acc8w(a, r2, rsqrtf((float)scl[s2] + 1.0f));
            acc8w(a, r3, rsqrtf((float)scl[s3] + 1.0f));
            acc8w(a, r4, rsqrtf((float)scl[s4] + 1.0f));
            acc8w(a, r5, rsqrtf((float)scl[s5] + 1.0f));
            acc8w(a, r6, rsqrtf((float)scl[s6] + 1.0f));
            acc8w(a, r7, rsqrtf((float)scl[s7] + 1.0f));
        }
        for (; k + 3 < deg; k += 4) {
            uint2 bw = *reinterpret_cast<const uint2*>(&bk[k]);
            int s0 = bw.x & 0xffff, s1 = bw.x >> 16;
            int s2 = bw.y & 0xffff, s3 = bw.y >> 16;
            uint4 r0 = base[(size_t)s0 * 16 + j];
            uint4 r1 = base[(size_t)s1 * 16 + j];
            uint4 r2 = base[(size_t)s2 * 16 + j];
            uint4 r3 = base[(size_t)s3 * 16 + j];
            acc8w(a, r0, rsqrtf((float)scl[s0] + 1.0f));
            acc8w(a, r1, rsqrtf((float)scl[s1] + 1.0f));
            acc8w(a, r2, rsqrtf((float)scl[s2] + 1.0f));
            acc8w(a, r3, rsqrtf((float)scl[s3] + 1.0f));
        }
        for (; k < deg; ++k) {
            int s0 = bk[k];
            uint4 r0 = base[(size_t)s0 * 16 + j];
            acc8w(a, r0, rsqrtf((float)scl[s0] + 1.0f));
        }
    } else {
        for (; k + 7 < deg; k += 8) {
            uint4 bw = *reinterpret_cast<const uint4*>(&bk[k]);
            int s0 = bw.x & 0xffff, s1 = bw.x >> 16;
            int s2 = bw.y & 0xffff, s3 = bw.y >> 16;
            int s4 = bw.z & 0xffff, s5 = bw.z >> 16;
            int s6 = bw.w & 0xffff, s7 = bw.w >> 16;
            uint4 r0 = base[(size_t)s0 * 16 + j];
            uint4 r1 = base[(size_t)s1 * 16 + j];
            uint4 r2 = base[(size_t)s2 * 16 + j];
            uint4 r3 = base[(size_t)s3 * 16 + j];
            uint4 r4 = base[(size_t)s4 * 16 + j];
            uint4 r5 = base[(size_t)s5 * 16 + j];
            uint4 r6 = base[(size_t)s6 * 16 + j];
            uint4 r7 = base[(size_t)s7 * 16 + j];
            acc8p(a, r0); acc8p(a, r1); acc8p(a, r2); acc8p(a, r3);
            acc8p(a, r4); acc8p(a, r5); acc8p(a, r6); acc8p(a, r7);
        }
        for (; k + 3 < deg; k += 4) {
            uint2 bw = *reinterpret_cast<const uint2*>(&bk[k]);
            int s0 = bw.x & 0xffff, s1 = bw.x >> 16;
            int s2 = bw.y & 0xffff, s3 = bw.y >> 16;
            uint4 r0 = base[(size_t)s0 * 16 + j];
            uint4 r1 = base[(size_t)s1 * 16 + j];
            uint4 r2 = base[(size_t)s2 * 16 + j];
            uint4 r3 = base[(size_t)s3 * 16 + j];
            acc8p(a, r0); acc8p(a, r1); acc8p(a, r2); acc8p(a, r3);
        }
        for (; k < deg; ++k) {
            uint4 r0 = base[(size_t)bk[k] * 16 + j];
            acc8p(a, r0);
        }
    }
    float b[8];
    if (flags[0]) {
        uint4 bb = ((const uint4*)bias)[j];
        b[0] = bflo(bb.x); b[1] = bfhi(bb.x);
        b[2] = bflo(bb.y); b[3] = bfhi(bb.y);
        b[4] = bflo(bb.z); b[5] = bfhi(bb.z);
        b[6] = bflo(bb.w); b[7] = bfhi(bb.w);
    } else {
        float4 f0 = ((const float4*)bias)[2 * j];
        float4 f1 = ((const float4*)bias)[2 * j + 1];
        b[0] = f0.x; b[1] = f0.y; b[2] = f0.z; b[3] = f0.w;
        b[4] = f1.x; b[5] = f1.y; b[6] = f1.z; b[7] = f1.w;
    }
    uintx4 ov;
#pragma unroll
    for (int i2 = 0; i2 < 4; ++i2) {
        float r0 = fmaxf(a[2 * i2]     * dn + b[2 * i2],     0.0f);
        float r1 = fmaxf(a[2 * i2 + 1] * dn + b[2 * i2 + 1], 0.0f);
        ov[i2] = (unsigned int)f2bfbits(r0) | ((unsigned int)f2bfbits(r1) << 16);
    }
    __builtin_nontemporal_store(ov,
        reinterpret_cast<uintx4*>(outh16 + (size_t)n * 128 + j * 8));
}

// ---------------- fallback (round-3 proven) atomic-scatter path ----------------
__global__ __launch_bounds__(256) void k_gemm(const void* __restrict__ A,
                                              const void* __restrict__ W,
                                              const int* __restrict__ flags,
                                              int a_uses_flag,
                                              float* __restrict__ out, int M) {
    __shared__ __align__(16) float Al[32 * 128];
    const int tid = threadIdx.x;
    const int F = flags[0];
    const int afmt = a_uses_flag ? F : 0;
    const int row0 = blockIdx.x * 32;
#pragma unroll
    for (int j = 0; j < 16; ++j) {
        int idx = j * 256 + tid;
        int r = idx >> 7, k = idx & 127;
        int gr = row0 + r;
        float v = 0.0f;
        if (gr < M) {
            size_t off = (size_t)gr * 128 + k;
            v = afmt ? bfbits2f(((const unsigned short*)A)[off])
                     : ((const float*)A)[off];
        }
        Al[idx] = v;
    }
    __syncthreads();
    const int tx = tid & 31, ty = tid >> 5;
    const int c0 = tx * 4;
    float acc[4][4] = {};
    if (F) {
        const ushort4* __restrict__ Wg = (const ushort4*)W;
#pragma unroll 4
        for (int k = 0; k < 128; ++k) {
            ushort4 wv = Wg[k * 32 + tx];
            float w0 = bfbits2f(wv.x), w1 = bfbits2f(wv.y);
            float w2 = bfbits2f(wv.z), w3 = bfbits2f(wv.w);
#pragma unroll
            for (int i = 0; i < 4; ++i) {
                float a = Al[(ty + i * 8) * 128 + k];
                acc[i][0] = fmaf(a, w0, acc[i][0]);
                acc[i][1] = fmaf(a, w1, acc[i][1]);
                acc[i][2] = fmaf(a, w2, acc[i][2]);
                acc[i][3] = fmaf(a, w3, acc[i][3]);
            }
        }
    } else {
        const float4* __restrict__ Wg = (const float4*)W;
#pragma unroll 4
        for (int k = 0; k < 128; ++k) {
            float4 wv = Wg[k * 32 + tx];
#pragma unroll
            for (int i = 0; i < 4; ++i) {
                float a = Al[(ty + i * 8) * 128 + k];
                acc[i][0] = fmaf(a, wv.x, acc[i][0]);
                acc[i][1] = fmaf(a, wv.y, acc[i][1]);
                acc[i][2] = fmaf(a, wv.z, acc[i][2]);
                acc[i][3] = fmaf(a, wv.w, acc[i][3]);
            }
        }
    }
#pragma unroll
    for (int i = 0; i < 4; ++i) {
        int gr = row0 + ty + i * 8;
        if (gr < M) {
            *reinterpret_cast<float4*>(&out[(size_t)gr * 128 + c0]) =
                make_float4(acc[i][0], acc[i][1], acc[i][2], acc[i][3]);
        }
    }
}
__global__ void k_deg_init(float* __restrict__ deg) {
    int i = blockIdx.x * 256 + threadIdx.x;
    if (i < NNODES) deg[i] = 1.0f;
}
__global__ void k_deg_edges(const int* __restrict__ ei, const int* __restrict__ flags,
                            float* __restrict__ deg) {
    int e = blockIdx.x * 256 + threadIdx.x;
    if (e < NEDGES) unsafeAtomicAdd(&deg[ld_idx(ei, NEDGES + e, flags[1])], 1.0f);
}
__global__ void k_rsqrt(float* __restrict__ deg) {
    int i = blockIdx.x * 256 + threadIdx.x;
    if (i < NNODES) deg[i] = 1.0f / sqrtf(deg[i]);
}
__global__ void k_selfloop(const float* __restrict__ tmp, const float* __restrict__ dinv,
                           float* __restrict__ agg) {
    int t = blockIdx.x * 256 + threadIdx.x;
    if (t >= NNODES * 32) return;
    int n = t >> 5, j = t & 31;
    float s = dinv[n]; s = s * s;
    float4 v = *reinterpret_cast<const float4*>(&tmp[(size_t)n * 128 + j * 4]);
    v.x *= s; v.y *= s; v.z *= s; v.w *= s;
    *reinterpret_cast<float4*>(&agg[(size_t)n * 128 + j * 4]) = v;
}
__global__ __launch_bounds__(256) void k_scatter(const int* __restrict__ ei,
                                                 const int* __restrict__ flags,
                                                 const float* __restrict__ dinv,
                                                 const float* __restrict__ tmp,
                                                 float* __restrict__ agg) {
    int t = blockIdx.x * 256 + threadIdx.x;
    int e = t >> 5;
    if (e >= NEDGES) return;
    int j = t & 31;
    int wide = flags[1];
    int s = ld_idx(ei, e, wide);
    int d = ld_idx(ei, NEDGES + e, wide);
    float w = dinv[s] * dinv[d];
    const float4 v = *reinterpret_cast<const float4*>(&tmp[(size_t)s * 128 + j * 4]);
    float* p = &agg[(size_t)d * 128 + j * 4];
    unsafeAtomicAdd(p + 0, v.x * w);
    unsafeAtomicAdd(p + 1, v.y * w);
    unsafeAtomicAdd(p + 2, v.z * w);
    unsafeAtomicAdd(p + 3, v.w * w);
}
__global__ void k_bias_relu(float* __restrict__ h, const void* __restrict__ b,
                            const int* __restrict__ flags) {
    int t = blockIdx.x * 256 + threadIdx.x;
    if (t >= NNODES * 32) return;
    int j = t & 31;
    float b0, b1, b2, b3;
    if (flags[0]) {
        const unsigned short* bb = (const unsigned short*)b;
        b0 = bfbits2f(bb[j * 4 + 0]); b1 = bfbits2f(bb[j * 4 + 1]);
        b2 = bfbits2f(bb[j * 4 + 2]); b3 = bfbits2f(bb[j * 4 + 3]);
    } else {
        const float* bb = (const float*)b;
        b0 = bb[j * 4 + 0]; b1 = bb[j * 4 + 1]; b2 = bb[j * 4 + 2]; b3 = bb[j * 4 + 3];
    }
    float4 v = *reinterpret_cast<float4*>(&h[(size_t)t * 4]);
    v.x = fmaxf(v.x + b0, 0.0f);
    v.y = fmaxf(v.y + b1, 0.0f);
    v.z = fmaxf(v.z + b2, 0.0f);
    v.w = fmaxf(v.w + b3, 0.0f);
    *reinterpret_cast<float4*>(&h[(size_t)t * 4]) = v;
}

// ---------------- pooling ----------------
__global__ void k_bounds(const int* __restrict__ batch, const int* __restrict__ flags,
                         int* __restrict__ bounds) {
    int g = threadIdx.x;
    if (g > NGRAPH) return;
    int wide = flags[1];
    int lo = 0, hi = NNODES;
    while (lo < hi) {
        int mid = (lo + hi) >> 1;
        if (ld_idx(batch, mid, wide) < g) lo = mid + 1; else hi = mid;
    }
    bounds[g] = lo;
}

// stage 1: 256 blocks = 4 segments x 64 graphs; bf16 h input; fp32 partials.
__global__ __launch_bounds__(256) void k_pool_part(const unsigned short* __restrict__ h16,
                                                   const int* __restrict__ bounds,
                                                   float* __restrict__ part) {
    __shared__ float sh[256 * 4];
    int g = blockIdx.x >> 2, seg = blockIdx.x & 3;
    int t = threadIdx.x;
    int c4 = t & 31, sub = t >> 5;  // sub in [0,8)
    int beg = bounds[g], end = bounds[g + 1];
    const ushort4* __restrict__ base = (const ushort4*)h16;
    float ax = 0, ay = 0, az = 0, aw = 0;
    for (int r = beg + seg * 8 + sub; r < end; r += 32) {
        ushort4 u = base[(size_t)r * 32 + c4];
        ax += bfbits2f(u.x); ay += bfbits2f(u.y);
        az += bfbits2f(u.z); aw += bfbits2f(u.w);
    }
    sh[t * 4 + 0] = ax; sh[t * 4 + 1] = ay; sh[t * 4 + 2] = az; sh[t * 4 + 3] = aw;
    __syncthreads();
    if (t < 32) {
        float4 r = make_float4(0, 0, 0, 0);
#pragma unroll
        for (int s = 0; s < 8; ++s) {
            r.x += sh[(s * 32 + t) * 4 + 0];
            r.y += sh[(s * 32 + t) * 4 + 1];
            r.z += sh[(s * 32 + t) * 4 + 2];
            r.w += sh[(s * 32 + t) * 4 + 3];
        }
        *reinterpret_cast<float4*>(&part[((size_t)(g * 4 + seg)) * 128 + t * 4]) = r;
    }
}

__global__ void k_pool_final(const float* __restrict__ part, const int* __restrict__ bounds,
                             const int* __restrict__ flags, void* __restrict__ out) {
    int i = blockIdx.x * 256 + threadIdx.x;
    if (i >= NGRAPH * 128) return;
    int g = i >> 7, col = i & 127;
    float s = part[(g * 4 + 0) * 128 + col] + part[(g * 4 + 1) * 128 + col] +
              part[(g * 4 + 2) * 128 + col] + part[(g * 4 + 3) * 128 + col];
    float c = (float)(bounds[g + 1] - bounds[g]);
    float r = s / fmaxf(c, 1.0f);
    if (flags[0]) ((__hip_bfloat16*)out)[i] = __float2bfloat16(r);
    else          ((float*)out)[i] = r;
}

// fallback pool (fp32 h)
__global__ __launch_bounds__(1024) void k_pool2(const float* __restrict__ h,
                                                const int* __restrict__ bounds,
                                                const int* __restrict__ flags,
                                                void* __restrict__ out) {
    __shared__ float sh[1024];
    int g = blockIdx.x;
    int t = threadIdx.x;
    int beg = bounds[g], end = bounds[g + 1];
    int col = t & 127, seg = t >> 7;
    float acc = 0.0f;
    for (int r = beg + seg; r < end; r += 8)
        acc += h[(size_t)r * 128 + col];
    sh[t] = acc;
    __syncthreads();
    if (t < 128) {
        float total = 0.0f;
#pragma unroll
        for (int i = 0; i < 8; ++i) total += sh[t + 128 * i];
        float c = (float)(end - beg);
        float r = total / fmaxf(c, 1.0f);
        if (flags[0]) ((__hip_bfloat16*)out)[g * 128 + t] = __float2bfloat16(r);
        else          ((float*)out)[g * 128 + t] = r;
    }
}

extern "C" void kernel_launch(void* const* d_in, const int* in_sizes, int n_in,
                              void* d_out, int out_size, void* d_ws, size_t ws_size,
                              hipStream_t stream) {
    const void* x  = d_in[0];
    const int* ei  = (const int*)d_in[1];
    const int* bat = (const int*)d_in[2];
    const void* W0 = d_in[3];
    const void* b0 = d_in[4];
    const void* W1 = d_in[5];
    const void* b1 = d_in[6];
    const void* W2 = d_in[7];
    const void* b2 = d_in[8];

    // Workspace: flags | dinv | hA-region(6.4M f) | hB-region(6.4M f) | bounds | cnt | part
    // CSR path overlays: hA16 = first half of hA-region; ecol(ushort, 6.4MB) in second half;
    // hB16 = first half of hB-region.
    float* ws = (float*)d_ws;
    size_t off = 0;
    int*   flags  = (int*)ws;           off += 16;
    float* dinv   = ws + off;           off += 50176;
    float* hA     = ws + off;           off += (size_t)NNODES * 128;
    float* hB     = ws + off;           off += (size_t)NNODES * 128;
    int*   bounds = (int*)(ws + off);   off += 80;
    int*   cnt    = (int*)(ws + off);   off += 50304;
    float* part   = ws + off;           off += NGRAPH * 4 * 128 + 64;
    const size_t needed = off * 4;
    unsigned short* hA16 = (unsigned short*)hA;
    unsigned short* hB16 = (unsigned short*)hB;
    unsigned short* ecol = (unsigned short*)(hA + (size_t)NNODES * 64);  // 3.2M ushorts

    const int bN  = (NNODES + 255) / 256;       // 196
    const int bE  = (NEDGES + 255) / 256;       // 3125
    const int bNF = (NNODES * 32) / 256;        // 6250
    const int bEF = (NEDGES * 32) / 256;        // 100000
    const int bGT = (NNODES * 16) / 256;        // 3125 (gather, 16 lanes/node)
    const int bG  = (NNODES + 31) / 32;         // 1563 (vector gemm)
    const int bG2 = (NNODES + 63) / 64;         // 782  (mfma gemm)
    dim3 blk(256);

    const bool use_csr = (ws_size >= needed);

    if (use_csr) {
        // init (zero cnt + detect) -> merged [append+bounds | gemm0-unscaled]
        hipLaunchKernelGGL(k_init, dim3(bN), blk, 0, stream,
                           (const unsigned int*)x, (const unsigned int*)ei, flags, cnt);
        hipLaunchKernelGGL(k_g0a, dim3(392 + bG2), blk, 0, stream,
                           ei, bat, flags, cnt, ecol, bounds, x, W0, hA16, NNODES);

        // layer 1: explicit-dinv gather; layers 2,3: prescaled-in-gemm
        hipLaunchKernelGGL(k_gather, dim3(bGT), blk, 0, stream, cnt, ecol, hA16, b0, flags, cnt, hB16);
        hipLaunchKernelGGL(k_gemm_mfma, dim3(bG2), blk, 0, stream, hB16, W1, flags, 2, cnt, hA16, NNODES);
        hipLaunchKernelGGL(k_gather, dim3(bGT), blk, 0, stream, cnt, ecol, hA16, b1, flags, (const int*)nullptr, hB16);
        hipLaunchKernelGGL(k_gemm_mfma, dim3(bG2), blk, 0, stream, hB16, W2, flags, 2, cnt, hA16, NNODES);
        hipLaunchKernelGGL(k_gather, dim3(bGT), blk, 0, stream, cnt, ecol, hA16, b2, flags, (const int*)nullptr, hB16);

        // pool: 2-stage reduce (bounds computed in k_g0a)
        hipLaunchKernelGGL(k_pool_part, dim3(NGRAPH * 4), blk, 0, stream, hB16, bounds, part);
        hipLaunchKernelGGL(k_pool_final, dim3(32), blk, 0, stream, part, bounds, flags, d_out);
    } else {
        // fallback: round-3 proven atomic path (fp32 everywhere)
        hipLaunchKernelGGL(k_detect, dim3(1), blk, 0, stream,
                           (const unsigned int*)x, (const unsigned int*)ei, flags);
        hipLaunchKernelGGL(k_deg_init, dim3(bN), blk, 0, stream, dinv);
        hipLaunchKernelGGL(k_deg_edges, dim3(bE), blk, 0, stream, ei, flags, dinv);
        hipLaunchKernelGGL(k_rsqrt, dim3(bN), blk, 0, stream, dinv);

        hipLaunchKernelGGL(k_gemm, dim3(bG), blk, 0, stream, x, W0, flags, 1, hA, NNODES);
        hipLaunchKernelGGL(k_selfloop, dim3(bNF), blk, 0, stream, hA, dinv, hB);
        hipLaunchKernelGGL(k_scatter, dim3(bEF), blk, 0, stream, ei, flags, dinv, hA, hB);
        hipLaunchKernelGGL(k_bias_relu, dim3(bNF), blk, 0, stream, hB, b0, flags);

        hipLaunchKernelGGL(k_gemm, dim3(bG), blk, 0, stream, hB, W1, flags, 0, hA, NNODES);
        hipLaunchKernelGGL(k_selfloop, dim3(bNF), blk, 0, stream, hA, dinv, hB);
        hipLaunchKernelGGL(k_scatter, dim3(bEF), blk, 0, stream, ei, flags, dinv, hA, hB);
        hipLaunchKernelGGL(k_bias_relu, dim3(bNF), blk, 0, stream, hB, b1, flags);

        hipLaunchKernelGGL(k_gemm, dim3(bG), blk, 0, stream, hB, W2, flags, 0, hA, NNODES);
        hipLaunchKernelGGL(k_selfloop, dim3(bNF), blk, 0, stream, hA, dinv, hB);
        hipLaunchKernelGGL(k_scatter, dim3(bEF), blk, 0, stream, ei, flags, dinv, hA, hB);
        hipLaunchKernelGGL(k_bias_relu, dim3(bNF), blk, 0, stream, hB, b2, flags);

        hipLaunchKernelGGL(k_bounds, dim3(1), dim3(128), 0, stream, bat, flags, bounds);
        hipLaunchKernelGGL(k_pool2, dim3(NGRAPH), dim3(1024), 0, stream, hB, bounds, flags, d_out);
    }
}

// Round 7
// 310.456 us; speedup vs baseline: 1.0998x; 1.0314x over previous
//
#include <hip/hip_runtime.h>
#include <hip/hip_bf16.h>

#define NNODES 50000
#define NEDGES 800000
#define HIDDIM 128
#define NGRAPH 64
#define BUCKET 64   // fixed CSR bucket capacity (mean deg 16, P(deg>=64)~2e-18)
#define NRANGE 196  // destination ranges of 256 nodes (r = d>>8)
#define RCAP 6144   // per-range segment capacity (mean 4081, +32 sigma)

typedef __attribute__((ext_vector_type(8))) short short8;
typedef __attribute__((ext_vector_type(4))) float floatx4;
typedef __attribute__((ext_vector_type(4))) unsigned int uintx4;

__device__ __forceinline__ float bfbits2f(unsigned short u) {
    return __uint_as_float(((unsigned int)u) << 16);
}
__device__ __forceinline__ unsigned short f2bfbits(float v) {
    __hip_bfloat16 h = __float2bfloat16(v);
    return __builtin_bit_cast(unsigned short, h);
}
__device__ __forceinline__ float bflo(unsigned int w) { return __uint_as_float(w << 16); }
__device__ __forceinline__ float bfhi(unsigned int w) { return __uint_as_float(w & 0xffff0000u); }

__device__ __forceinline__ void acc8w(float* __restrict__ a, uint4 r, float wt) {
    a[0] = fmaf(wt, bflo(r.x), a[0]); a[1] = fmaf(wt, bfhi(r.x), a[1]);
    a[2] = fmaf(wt, bflo(r.y), a[2]); a[3] = fmaf(wt, bfhi(r.y), a[3]);
    a[4] = fmaf(wt, bflo(r.z), a[4]); a[5] = fmaf(wt, bfhi(r.z), a[5]);
    a[6] = fmaf(wt, bflo(r.w), a[6]); a[7] = fmaf(wt, bfhi(r.w), a[7]);
}
__device__ __forceinline__ void acc8p(float* __restrict__ a, uint4 r) {
    a[0] += bflo(r.x); a[1] += bfhi(r.x);
    a[2] += bflo(r.y); a[3] += bfhi(r.y);
    a[4] += bflo(r.z); a[5] += bfhi(r.z);
    a[6] += bflo(r.w); a[7] += bfhi(r.w);
}

__device__ __forceinline__ int ld_idx(const int* __restrict__ p, int j, int wide) {
    return wide ? p[2 * j] : p[j];
}

// ---------------- runtime dtype detection ----------------
// flags[0]=1: floats stored bf16; 0: fp32.  flags[1]=1: indices int64; 0: int32.
__global__ void k_detect(const unsigned int* __restrict__ xw,
                         const unsigned int* __restrict__ eiw,
                         int* __restrict__ flags) {
    __shared__ int sh_hit, sh_zero;
    int t = threadIdx.x;
    if (t == 0) { sh_hit = 0; sh_zero = 0; }
    __syncthreads();
    if (t < 128) {
        unsigned int w = xw[t * 97 + 5];
        int e = (int)((w >> 7) & 0xFF);
        if (e >= 110 && e <= 140) atomicAdd(&sh_hit, 1);
        if (eiw[1001 + 2 * t] == 0) atomicAdd(&sh_zero, 1);
    }
    __syncthreads();
    if (t == 0) {
        flags[0] = (sh_hit >= 64) ? 1 : 0;
        flags[1] = (sh_zero >= 120) ? 1 : 0;
    }
}

// CSR-path init: detect + zero rangecnt (196 ints). Single block.
__global__ void k_init(const unsigned int* __restrict__ xw,
                       const unsigned int* __restrict__ eiw,
                       int* __restrict__ flags, int* __restrict__ rangecnt) {
    __shared__ int sh_hit, sh_zero;
    int t = threadIdx.x;
    if (t < NRANGE) rangecnt[t] = 0;
    if (t == 0) { sh_hit = 0; sh_zero = 0; }
    __syncthreads();
    if (t < 128) {
        unsigned int w = xw[t * 97 + 5];
        int e = (int)((w >> 7) & 0xFF);
        if (e >= 110 && e <= 140) atomicAdd(&sh_hit, 1);
        if (eiw[1001 + 2 * t] == 0) atomicAdd(&sh_zero, 1);
    }
    __syncthreads();
    if (t == 0) {
        flags[0] = (sh_hit >= 64) ? 1 : 0;
        flags[1] = (sh_zero >= 120) ? 1 : 0;
    }
}

// ---------------- radix build phase 1: partition edges by destination range -----
// Block b handles edges [b*2048, b*2048+2048). LDS-bin by r=d>>8, reserve chunk in
// the per-range global segment with ONE atomicAdd per (block,range) (77K total vs
// 800K), write bin-ordered packed words: consecutive staging slots -> consecutive
// global addresses (no scattered-line writeback). Last block computes pool bounds.
__global__ __launch_bounds__(256) void k_part1(const int* __restrict__ ei,
                                               const int* __restrict__ bat,
                                               const int* __restrict__ flags,
                                               int* __restrict__ rangecnt,
                                               unsigned int* __restrict__ pairs,
                                               int* __restrict__ bounds) {
    if (blockIdx.x == gridDim.x - 1) {  // pool bounds (binary search per graph)
        int g = threadIdx.x;
        if (g > NGRAPH) return;
        int wide = flags[1];
        int lo = 0, hi = NNODES;
        while (lo < hi) {
            int mid = (lo + hi) >> 1;
            if (ld_idx(bat, mid, wide) < g) lo = mid + 1; else hi = mid;
        }
        bounds[g] = lo;
        return;
    }
    __shared__ int lcnt[NRANGE];
    __shared__ int lbase[NRANGE];
    __shared__ int lpos[NRANGE];
    __shared__ int gchunk[NRANGE];
    __shared__ unsigned int stg[2048];
    const int tid = threadIdx.x;
    if (tid < NRANGE) lcnt[tid] = 0;
    __syncthreads();

    int T = blockIdx.x * 256 + tid;
    int e0 = T * 8;
    const bool live = (e0 < NEDGES);  // NEDGES%8==0: live threads own full groups
    int s[8], d[8];
    if (live) {
        int wide = flags[1];
        if (wide) {
            const int4* __restrict__ sp = (const int4*)ei;
            const int4* __restrict__ dp = (const int4*)(ei + 2 * NEDGES);
#pragma unroll
            for (int q = 0; q < 4; ++q) {
                int4 sv = sp[T * 4 + q]; s[2 * q] = sv.x; s[2 * q + 1] = sv.z;
                int4 dv = dp[T * 4 + q]; d[2 * q] = dv.x; d[2 * q + 1] = dv.z;
            }
        } else {
            const int4* __restrict__ sp = (const int4*)ei;
            const int4* __restrict__ dp = (const int4*)(ei + NEDGES);
#pragma unroll
            for (int q = 0; q < 2; ++q) {
                int4 sv = sp[T * 2 + q];
                s[4 * q] = sv.x; s[4 * q + 1] = sv.y; s[4 * q + 2] = sv.z; s[4 * q + 3] = sv.w;
                int4 dv = dp[T * 2 + q];
                d[4 * q] = dv.x; d[4 * q + 1] = dv.y; d[4 * q + 2] = dv.z; d[4 * q + 3] = dv.w;
            }
        }
#pragma unroll
        for (int q = 0; q < 8; ++q) atomicAdd(&lcnt[d[q] >> 8], 1);
    }
    __syncthreads();
    if (tid == 0) {  // serial prefix over 196 bins (hidden by cross-block overlap)
        int run = 0;
        for (int i = 0; i < NRANGE; ++i) {
            lbase[i] = run; lpos[i] = run; run += lcnt[i];
        }
    }
    __syncthreads();
    if (tid < NRANGE) {
        int c = lcnt[tid];
        gchunk[tid] = (c > 0) ? atomicAdd(&rangecnt[tid], c) : 0;
    }
    __syncthreads();
    if (live) {
#pragma unroll
        for (int q = 0; q < 8; ++q) {
            int r = d[q] >> 8;
            int p = atomicAdd(&lpos[r], 1);
            stg[p] = ((unsigned)r << 24) | (((unsigned)d[q] & 255u) << 16) |
                     ((unsigned)s[q] & 0xffffu);
        }
    }
    __syncthreads();
    const int total = lbase[NRANGE - 1] + lcnt[NRANGE - 1];
    for (int p = tid; p < total; p += 256) {
        unsigned w = stg[p];
        int r = (int)(w >> 24);
        int off = gchunk[r] + (p - lbase[r]);
        if (off < RCAP) pairs[(size_t)r * RCAP + off] = w;
    }
}

// ---------------- radix build phase 2: segment -> LDS buckets -> coalesced ecol ---
// Block r: read range segment (coalesced), LDS-atomic bin into 256-node bucket
// array (32 KB), write the range's ecol slab with uint4 stores + cnt. Garbage in
// slots beyond cnt[n] is never read.
__global__ __launch_bounds__(256) void k_part2(const int* __restrict__ rangecnt,
                                               const unsigned int* __restrict__ pairs,
                                               unsigned short* __restrict__ ecol,
                                               int* __restrict__ cnt) {
    __shared__ __align__(16) unsigned short lb[256 * BUCKET];  // 32 KB
    __shared__ int lc[256];
    const int r = blockIdx.x;
    const int tid = threadIdx.x;
    lc[tid] = 0;
    __syncthreads();
    int n_r = rangecnt[r];
    if (n_r > RCAP) n_r = RCAP;
    for (int p = tid; p < n_r; p += 256) {
        unsigned w = pairs[(size_t)r * RCAP + p];
        int dlow = (int)((w >> 16) & 0xffu);
        int pos = atomicAdd(&lc[dlow], 1);
        if (pos < BUCKET) lb[dlow * BUCKET + pos] = (unsigned short)(w & 0xffffu);
    }
    __syncthreads();
    const int node0 = r * 256;
    int vn = NNODES - node0; if (vn > 256) vn = 256;  // last range: 80 valid nodes
    if (tid < vn) cnt[node0 + tid] = lc[tid];
    const uintx4* __restrict__ src = reinterpret_cast<const uintx4*>(lb);
    uintx4* __restrict__ dst = reinterpret_cast<uintx4*>(ecol + (size_t)node0 * BUCKET);
    const int nvec = vn * 8;  // 64 ushorts = 8 uint4 per node
    for (int i = tid; i < nvec; i += 256) dst[i] = src[i];
}

// ---------------- MFMA GEMM: out_bf16[M,128] = (A @ W) * rsqrt(cnt[m]+1) ----------
// a_mode: 0=fp32 A, 1=A follows flags[0], 2=A is bf16 bits.
__global__ __launch_bounds__(256) void k_gemm_mfma(const void* __restrict__ A,
                                                   const void* __restrict__ W,
                                                   const int* __restrict__ flags,
                                                   int a_mode,
                                                   const int* __restrict__ degcnt,
                                                   unsigned short* __restrict__ out,
                                                   int M) {
    __shared__ __align__(16) unsigned short Wl[16 * 128 * 8];   // 32 KB: [kb][n][j]
    __shared__ __align__(16) unsigned short Alds[64 * 17 * 8];  // 17 KB: [m][kb(+pad)][j]
    const int tid = threadIdx.x;
    const int F = flags[0];
    const int abf = (a_mode == 2) ? 1 : (a_mode == 1 ? F : 0);
    const int row0 = blockIdx.x * 64;

    if (F) {
        const ushort4* __restrict__ Wg = (const ushort4*)W;
#pragma unroll
        for (int it = 0; it < 16; ++it) {
            int idx = it * 256 + tid;
            int k = idx >> 5, n = (idx & 31) * 4;
            ushort4 wv = Wg[idx];
            unsigned short* dst = &Wl[(((k >> 3) * 128) + n) * 8 + (k & 7)];
            dst[0] = wv.x; dst[8] = wv.y; dst[16] = wv.z; dst[24] = wv.w;
        }
    } else {
        const float4* __restrict__ Wg = (const float4*)W;
#pragma unroll
        for (int it = 0; it < 16; ++it) {
            int idx = it * 256 + tid;
            int k = idx >> 5, n = (idx & 31) * 4;
            float4 wv = Wg[idx];
            unsigned short* dst = &Wl[(((k >> 3) * 128) + n) * 8 + (k & 7)];
            dst[0] = f2bfbits(wv.x); dst[8]  = f2bfbits(wv.y);
            dst[16] = f2bfbits(wv.z); dst[24] = f2bfbits(wv.w);
        }
    }
    if (abf) {
#pragma unroll
        for (int it = 0; it < 4; ++it) {
            int idx = it * 256 + tid;          // m=idx>>4, kb=idx&15
            int m = idx >> 4, kb = idx & 15;
            int gr = row0 + m;
            uint4 v = make_uint4(0, 0, 0, 0);
            if (gr < M) v = ((const uint4*)A)[(size_t)gr * 16 + kb];
            *reinterpret_cast<uint4*>(&Alds[(m * 17 + kb) * 8]) = v;
        }
    } else {
#pragma unroll
        for (int it = 0; it < 8; ++it) {
            int idx = it * 256 + tid;          // m=idx>>5, k4=idx&31
            int m = idx >> 5, k4 = idx & 31;
            int k = k4 * 4;
            int gr = row0 + m;
            float4 v = make_float4(0, 0, 0, 0);
            if (gr < M) v = ((const float4*)A)[(size_t)gr * 32 + k4];
            ushort4 u;
            u.x = f2bfbits(v.x); u.y = f2bfbits(v.y);
            u.z = f2bfbits(v.z); u.w = f2bfbits(v.w);
            *reinterpret_cast<ushort4*>(&Alds[(m * 17 + (k >> 3)) * 8 + (k & 7)]) = u;
        }
    }
    __syncthreads();

    const int lane = tid & 63;
    const int wave = tid >> 6;
    const int q = lane >> 4;
    const int c = lane & 15;
    const int mrow = wave * 16 + c;
    floatx4 acc[8] = {};
#pragma unroll
    for (int k0 = 0; k0 < 4; ++k0) {
        int kb = k0 * 4 + q;
        short8 afrag = *reinterpret_cast<const short8*>(&Alds[(mrow * 17 + kb) * 8]);
#pragma unroll
        for (int t = 0; t < 8; ++t) {
            short8 bfrag = *reinterpret_cast<const short8*>(&Wl[(kb * 128 + t * 16 + c) * 8]);
            acc[t] = __builtin_amdgcn_mfma_f32_16x16x32_bf16(afrag, bfrag, acc[t], 0, 0, 0);
        }
    }
#pragma unroll
    for (int i = 0; i < 4; ++i) {
        int gr = row0 + wave * 16 + q * 4 + i;
        if (gr < M) {
            float s = degcnt ? rsqrtf((float)degcnt[gr] + 1.0f) : 1.0f;
#pragma unroll
            for (int t = 0; t < 8; ++t) {
                out[(size_t)gr * 128 + t * 16 + c] = f2bfbits(acc[t][i] * s);
            }
        }
    }
}

// ---------------- fused gather (bf16 in/out): row-sum + scale + bias + relu --------
// 16 lanes/node, 8-wide MLP deg loop (round-6 confirmed: latency-bound, ~34us).
__global__ __launch_bounds__(256) void k_gather(const int* __restrict__ cnt,
                                                const unsigned short* __restrict__ ecol,
                                                const unsigned short* __restrict__ tmp16,
                                                const void* __restrict__ bias,
                                                const int* __restrict__ flags,
                                                const int* __restrict__ scl,
                                                unsigned short* __restrict__ outh16) {
    int t = blockIdx.x * 256 + threadIdx.x;
    int n = t >> 4;
    if (n >= NNODES) return;
    int j = t & 15;  // 16B chunk = bf16 columns [j*8, j*8+8)
    int degf = cnt[n];
    float dn = rsqrtf((float)degf + 1.0f);
    int deg = degf > BUCKET ? BUCKET : degf;
    const unsigned short* __restrict__ bk = &ecol[(size_t)n * BUCKET];
    const uint4* __restrict__ base = reinterpret_cast<const uint4*>(tmp16);
    float a[8];
    {
        uint4 u = base[(size_t)n * 16 + j];  // self-loop term
        float w0 = scl ? dn : 1.0f;
        a[0] = w0 * bflo(u.x); a[1] = w0 * bfhi(u.x);
        a[2] = w0 * bflo(u.y); a[3] = w0 * bfhi(u.y);
        a[4] = w0 * bflo(u.z); a[5] = w0 * bfhi(u.z);
        a[6] = w0 * bflo(u.w); a[7] = w0 * bfhi(u.w);
    }
    int k = 0;
    if (scl) {
        for (; k + 7 < deg; k += 8) {
            uint4 bw = *reinterpret_cast<const uint4*>(&bk[k]);
            int s0 = bw.x & 0xffff, s1 = bw.x >> 16;
            int s2 = bw.y & 0xffff, s3 = bw.y >> 16;
            int s4 = bw.z & 0xffff, s5 = bw.z >> 16;
            int s6 = bw.w & 0xffff, s7 = bw.w >> 16;
            uint4 r0 = base[(size_t)s0 * 16 + j];
            uint4 r1 = base[(size_t)s1 * 16 + j];
            uint4 r2 = base[(size_t)s2 * 16 + j];
            uint4 r3 = base[(size_t)s3 * 16 + j];
            uint4 r4 = base[(size_t)s4 * 16 + j];
            uint4 r5 = base[(size_t)s5 * 16 + j];
            uint4 r6 = base[(size_t)s6 * 16 + j];
            uint4 r7 = base[(size_t)s7 * 16 + j];
            acc8w(a, r0, rsqrtf((float)scl[s0] + 1.0f));
            acc8w(a, r1, rsqrtf((float)scl[s1] + 1.0f));
            acc8w(a, r2, rsqrtf((float)scl[s2] + 1.0f));
            acc8w(a, r3, rsqrtf((float)scl[s3] + 1.0f));
            acc8w(a, r4, rsqrtf((float)scl[s4] + 1.0f));
            acc8w(a, r5, rsqrtf((float)scl[s5] + 1.0f));
            acc8w(a, r6, rsqrtf((float)scl[s6] + 1.0f));
            acc8w(a, r7, rsqrtf((float)scl[s7] + 1.0f));
        }
        for (; k < deg; ++k) {
            int s0 = bk[k];
            uint4 r0 = base[(size_t)s0 * 16 + j];
            acc8w(a, r0, rsqrtf((float)scl[s0] + 1.0f));
        }
    } else {
        for (; k + 7 < deg; k += 8) {
            uint4 bw = *reinterpret_cast<const uint4*>(&bk[k]);
            int s0 = bw.x & 0xffff, s1 = bw.x >> 16;
            int s2 = bw.y & 0xffff, s3 = bw.y >> 16;
            int s4 = bw.z & 0xffff, s5 = bw.z >> 16;
            int s6 = bw.w & 0xffff, s7 = bw.w >> 16;
            uint4 r0 = base[(size_t)s0 * 16 + j];
            uint4 r1 = base[(size_t)s1 * 16 + j];
            uint4 r2 = base[(size_t)s2 * 16 + j];
            uint4 r3 = base[(size_t)s3 * 16 + j];
            uint4 r4 = base[(size_t)s4 * 16 + j];
            uint4 r5 = base[(size_t)s5 * 16 + j];
            uint4 r6 = base[(size_t)s6 * 16 + j];
            uint4 r7 = base[(size_t)s7 * 16 + j];
            acc8p(a, r0); acc8p(a, r1); acc8p(a, r2); acc8p(a, r3);
            acc8p(a, r4); acc8p(a, r5); acc8p(a, r6); acc8p(a, r7);
        }
        for (; k + 3 < deg; k += 4) {
            uint2 bw = *reinterpret_cast<const uint2*>(&bk[k]);
            int s0 = bw.x & 0xffff, s1 = bw.x >> 16;
            int s2 = bw.y & 0xffff, s3 = bw.y >> 16;
            uint4 r0 = base[(size_t)s0 * 16 + j];
            uint4 r1 = base[(size_t)s1 * 16 + j];
            uint4 r2 = base[(size_t)s2 * 16 + j];
            uint4 r3 = base[(size_t)s3 * 16 + j];
            acc8p(a, r0); acc8p(a, r1); acc8p(a, r2); acc8p(a, r3);
        }
        for (; k < deg; ++k) {
            uint4 r0 = base[(size_t)bk[k] * 16 + j];
            acc8p(a, r0);
        }
    }
    float b[8];
    if (flags[0]) {
        uint4 bb = ((const uint4*)bias)[j];
        b[0] = bflo(bb.x); b[1] = bfhi(bb.x);
        b[2] = bflo(bb.y); b[3] = bfhi(bb.y);
        b[4] = bflo(bb.z); b[5] = bfhi(bb.z);
        b[6] = bflo(bb.w); b[7] = bfhi(bb.w);
    } else {
        float4 f0 = ((const float4*)bias)[2 * j];
        float4 f1 = ((const float4*)bias)[2 * j + 1];
        b[0] = f0.x; b[1] = f0.y; b[2] = f0.z; b[3] = f0.w;
        b[4] = f1.x; b[5] = f1.y; b[6] = f1.z; b[7] = f1.w;
    }
    uintx4 ov;
#pragma unroll
    for (int i2 = 0; i2 < 4; ++i2) {
        float r0 = fmaxf(a[2 * i2]     * dn + b[2 * i2],     0.0f);
        float r1 = fmaxf(a[2 * i2 + 1] * dn + b[2 * i2 + 1], 0.0f);
        ov[i2] = (unsigned int)f2bfbits(r0) | ((unsigned int)f2bfbits(r1) << 16);
    }
    __builtin_nontemporal_store(ov,
        reinterpret_cast<uintx4*>(outh16 + (size_t)n * 128 + j * 8));
}

// ---------------- fallback (round-3 proven) atomic-scatter path ----------------
__global__ __launch_bounds__(256) void k_gemm(const void* __restrict__ A,
                                              const void* __restrict__ W,
                                              const int* __restrict__ flags,
                                              int a_uses_flag,
                                              float* __restrict__ out, int M) {
    __shared__ __align__(16) float Al[32 * 128];
    const int tid = threadIdx.x;
    const int F = flags[0];
    const int afmt = a_uses_flag ? F : 0;
    const int row0 = blockIdx.x * 32;
#pragma unroll
    for (int j = 0; j < 16; ++j) {
        int idx = j * 256 + tid;
        int r = idx >> 7, k = idx & 127;
        int gr = row0 + r;
        float v = 0.0f;
        if (gr < M) {
            size_t off = (size_t)gr * 128 + k;
            v = afmt ? bfbits2f(((const unsigned short*)A)[off])
                     : ((const float*)A)[off];
        }
        Al[idx] = v;
    }
    __syncthreads();
    const int tx = tid & 31, ty = tid >> 5;
    const int c0 = tx * 4;
    float acc[4][4] = {};
    if (F) {
        const ushort4* __restrict__ Wg = (const ushort4*)W;
#pragma unroll 4
        for (int k = 0; k < 128; ++k) {
            ushort4 wv = Wg[k * 32 + tx];
            float w0 = bfbits2f(wv.x), w1 = bfbits2f(wv.y);
            float w2 = bfbits2f(wv.z), w3 = bfbits2f(wv.w);
#pragma unroll
            for (int i = 0; i < 4; ++i) {
                float a = Al[(ty + i * 8) * 128 + k];
                acc[i][0] = fmaf(a, w0, acc[i][0]);
                acc[i][1] = fmaf(a, w1, acc[i][1]);
                acc[i][2] = fmaf(a, w2, acc[i][2]);
                acc[i][3] = fmaf(a, w3, acc[i][3]);
            }
        }
    } else {
        const float4* __restrict__ Wg = (const float4*)W;
#pragma unroll 4
        for (int k = 0; k < 128; ++k) {
            float4 wv = Wg[k * 32 + tx];
#pragma unroll
            for (int i = 0; i < 4; ++i) {
                float a = Al[(ty + i * 8) * 128 + k];
                acc[i][0] = fmaf(a, wv.x, acc[i][0]);
                acc[i][1] = fmaf(a, wv.y, acc[i][1]);
                acc[i][2] = fmaf(a, wv.z, acc[i][2]);
                acc[i][3] = fmaf(a, wv.w, acc[i][3]);
            }
        }
    }
#pragma unroll
    for (int i = 0; i < 4; ++i) {
        int gr = row0 + ty + i * 8;
        if (gr < M) {
            *reinterpret_cast<float4*>(&out[(size_t)gr * 128 + c0]) =
                make_float4(acc[i][0], acc[i][1], acc[i][2], acc[i][3]);
        }
    }
}
__global__ void k_deg_init(float* __restrict__ deg) {
    int i = blockIdx.x * 256 + threadIdx.x;
    if (i < NNODES) deg[i] = 1.0f;
}
__global__ void k_deg_edges(const int* __restrict__ ei, const int* __restrict__ flags,
                            float* __restrict__ deg) {
    int e = blockIdx.x * 256 + threadIdx.x;
    if (e < NEDGES) unsafeAtomicAdd(&deg[ld_idx(ei, NEDGES + e, flags[1])], 1.0f);
}
__global__ void k_rsqrt(float* __restrict__ deg) {
    int i = blockIdx.x * 256 + threadIdx.x;
    if (i < NNODES) deg[i] = 1.0f / sqrtf(deg[i]);
}
__global__ void k_selfloop(const float* __restrict__ tmp, const float* __restrict__ dinv,
                           float* __restrict__ agg) {
    int t = blockIdx.x * 256 + threadIdx.x;
    if (t >= NNODES * 32) return;
    int n = t >> 5, j = t & 31;
    float s = dinv[n]; s = s * s;
    float4 v = *reinterpret_cast<const float4*>(&tmp[(size_t)n * 128 + j * 4]);
    v.x *= s; v.y *= s; v.z *= s; v.w *= s;
    *reinterpret_cast<float4*>(&agg[(size_t)n * 128 + j * 4]) = v;
}
__global__ __launch_bounds__(256) void k_scatter(const int* __restrict__ ei,
                                                 const int* __restrict__ flags,
                                                 const float* __restrict__ dinv,
                                                 const float* __restrict__ tmp,
                                                 float* __restrict__ agg) {
    int t = blockIdx.x * 256 + threadIdx.x;
    int e = t >> 5;
    if (e >= NEDGES) return;
    int j = t & 31;
    int wide = flags[1];
    int s = ld_idx(ei, e, wide);
    int d = ld_idx(ei, NEDGES + e, wide);
    float w = dinv[s] * dinv[d];
    const float4 v = *reinterpret_cast<const float4*>(&tmp[(size_t)s * 128 + j * 4]);
    float* p = &agg[(size_t)d * 128 + j * 4];
    unsafeAtomicAdd(p + 0, v.x * w);
    unsafeAtomicAdd(p + 1, v.y * w);
    unsafeAtomicAdd(p + 2, v.z * w);
    unsafeAtomicAdd(p + 3, v.w * w);
}
__global__ void k_bias_relu(float* __restrict__ h, const void* __restrict__ b,
                            const int* __restrict__ flags) {
    int t = blockIdx.x * 256 + threadIdx.x;
    if (t >= NNODES * 32) return;
    int j = t & 31;
    float b0, b1, b2, b3;
    if (flags[0]) {
        const unsigned short* bb = (const unsigned short*)b;
        b0 = bfbits2f(bb[j * 4 + 0]); b1 = bfbits2f(bb[j * 4 + 1]);
        b2 = bfbits2f(bb[j * 4 + 2]); b3 = bfbits2f(bb[j * 4 + 3]);
    } else {
        const float* bb = (const float*)b;
        b0 = bb[j * 4 + 0]; b1 = bb[j * 4 + 1]; b2 = bb[j * 4 + 2]; b3 = bb[j * 4 + 3];
    }
    float4 v = *reinterpret_cast<float4*>(&h[(size_t)t * 4]);
    v.x = fmaxf(v.x + b0, 0.0f);
    v.y = fmaxf(v.y + b1, 0.0f);
    v.z = fmaxf(v.z + b2, 0.0f);
    v.w = fmaxf(v.w + b3, 0.0f);
    *reinterpret_cast<float4*>(&h[(size_t)t * 4]) = v;
}

// ---------------- pooling ----------------
__global__ void k_bounds(const int* __restrict__ batch, const int* __restrict__ flags,
                         int* __restrict__ bounds) {
    int g = threadIdx.x;
    if (g > NGRAPH) return;
    int wide = flags[1];
    int lo = 0, hi = NNODES;
    while (lo < hi) {
        int mid = (lo + hi) >> 1;
        if (ld_idx(batch, mid, wide) < g) lo = mid + 1; else hi = mid;
    }
    bounds[g] = lo;
}

// stage 1: 256 blocks = 4 segments x 64 graphs; bf16 h input; fp32 partials.
__global__ __launch_bounds__(256) void k_pool_part(const unsigned short* __restrict__ h16,
                                                   const int* __restrict__ bounds,
                                                   float* __restrict__ part) {
    __shared__ float sh[256 * 4];
    int g = blockIdx.x >> 2, seg = blockIdx.x & 3;
    int t = threadIdx.x;
    int c4 = t & 31, sub = t >> 5;  // sub in [0,8)
    int beg = bounds[g], end = bounds[g + 1];
    const ushort4* __restrict__ base = (const ushort4*)h16;
    float ax = 0, ay = 0, az = 0, aw = 0;
    for (int r = beg + seg * 8 + sub; r < end; r += 32) {
        ushort4 u = base[(size_t)r * 32 + c4];
        ax += bfbits2f(u.x); ay += bfbits2f(u.y);
        az += bfbits2f(u.z); aw += bfbits2f(u.w);
    }
    sh[t * 4 + 0] = ax; sh[t * 4 + 1] = ay; sh[t * 4 + 2] = az; sh[t * 4 + 3] = aw;
    __syncthreads();
    if (t < 32) {
        float4 r = make_float4(0, 0, 0, 0);
#pragma unroll
        for (int s = 0; s < 8; ++s) {
            r.x += sh[(s * 32 + t) * 4 + 0];
            r.y += sh[(s * 32 + t) * 4 + 1];
            r.z += sh[(s * 32 + t) * 4 + 2];
            r.w += sh[(s * 32 + t) * 4 + 3];
        }
        *reinterpret_cast<float4*>(&part[((size_t)(g * 4 + seg)) * 128 + t * 4]) = r;
    }
}

__global__ void k_pool_final(const float* __restrict__ part, const int* __restrict__ bounds,
                             const int* __restrict__ flags, void* __restrict__ out) {
    int i = blockIdx.x * 256 + threadIdx.x;
    if (i >= NGRAPH * 128) return;
    int g = i >> 7, col = i & 127;
    float s = part[(g * 4 + 0) * 128 + col] + part[(g * 4 + 1) * 128 + col] +
              part[(g * 4 + 2) * 128 + col] + part[(g * 4 + 3) * 128 + col];
    float c = (float)(bounds[g + 1] - bounds[g]);
    float r = s / fmaxf(c, 1.0f);
    if (flags[0]) ((__hip_bfloat16*)out)[i] = __float2bfloat16(r);
    else          ((float*)out)[i] = r;
}

// fallback pool (fp32 h)
__global__ __launch_bounds__(1024) void k_pool2(const float* __restrict__ h,
                                                const int* __restrict__ bounds,
                                                const int* __restrict__ flags,
                                                void* __restrict__ out) {
    __shared__ float sh[1024];
    int g = blockIdx.x;
    int t = threadIdx.x;
    int beg = bounds[g], end = bounds[g + 1];
    int col = t & 127, seg = t >> 7;
    float acc = 0.0f;
    for (int r = beg + seg; r < end; r += 8)
        acc += h[(size_t)r * 128 + col];
    sh[t] = acc;
    __syncthreads();
    if (t < 128) {
        float total = 0.0f;
#pragma unroll
        for (int i = 0; i < 8; ++i) total += sh[t + 128 * i];
        float c = (float)(end - beg);
        float r = total / fmaxf(c, 1.0f);
        if (flags[0]) ((__hip_bfloat16*)out)[g * 128 + t] = __float2bfloat16(r);
        else          ((float*)out)[g * 128 + t] = r;
    }
}

extern "C" void kernel_launch(void* const* d_in, const int* in_sizes, int n_in,
                              void* d_out, int out_size, void* d_ws, size_t ws_size,
                              hipStream_t stream) {
    const void* x  = d_in[0];
    const int* ei  = (const int*)d_in[1];
    const int* bat = (const int*)d_in[2];
    const void* W0 = d_in[3];
    const void* b0 = d_in[4];
    const void* W1 = d_in[5];
    const void* b1 = d_in[6];
    const void* W2 = d_in[7];
    const void* b2 = d_in[8];

    // Workspace: flags | dinv | hA-region(6.4M f) | hB-region(6.4M f) | bounds | cnt | part
    // CSR overlays: hA16 = first half of hA; ecol (6.4MB) = second half of hA;
    // hB16 = first half of hB; pairs (4.8MB, radix scratch) = start of hB (dead
    // before the first gather writes hB16); rangecnt = dinv slot (ints).
    float* ws = (float*)d_ws;
    size_t off = 0;
    int*   flags  = (int*)ws;           off += 16;
    float* dinv   = ws + off;           off += 50176;
    float* hA     = ws + off;           off += (size_t)NNODES * 128;
    float* hB     = ws + off;           off += (size_t)NNODES * 128;
    int*   bounds = (int*)(ws + off);   off += 80;
    int*   cnt    = (int*)(ws + off);   off += 50304;
    float* part   = ws + off;           off += NGRAPH * 4 * 128 + 64;
    const size_t needed = off * 4;
    unsigned short* hA16 = (unsigned short*)hA;
    unsigned short* hB16 = (unsigned short*)hB;
    unsigned short* ecol = (unsigned short*)(hA + (size_t)NNODES * 64);  // 3.2M ushorts
    int* rangecnt = (int*)dinv;
    unsigned int* pairs = (unsigned int*)hB;   // 196*6144*4B = 4.8MB

    const int bN  = (NNODES + 255) / 256;       // 196
    const int bE  = (NEDGES + 255) / 256;       // 3125
    const int bNF = (NNODES * 32) / 256;        // 6250
    const int bEF = (NEDGES * 32) / 256;        // 100000
    const int bP1 = (NEDGES + 2047) / 2048;     // 391 (part1 edge blocks)
    const int bGT = (NNODES * 16) / 256;        // 3125 (gather, 16 lanes/node)
    const int bG  = (NNODES + 31) / 32;         // 1563 (vector gemm)
    const int bG2 = (NNODES + 63) / 64;         // 782  (mfma gemm)
    dim3 blk(256);

    const bool use_csr = (ws_size >= needed);

    if (use_csr) {
        // init (detect + zero rangecnt) -> radix partition build (+bounds)
        hipLaunchKernelGGL(k_init, dim3(1), blk, 0, stream,
                           (const unsigned int*)x, (const unsigned int*)ei, flags, rangecnt);
        hipLaunchKernelGGL(k_part1, dim3(bP1 + 1), blk, 0, stream,
                           ei, bat, flags, rangecnt, pairs, bounds);
        hipLaunchKernelGGL(k_part2, dim3(NRANGE), blk, 0, stream,
                           rangecnt, pairs, ecol, cnt);

        // layers (round-3 dataflow: prescaled gemm out, scl=null gathers)
        hipLaunchKernelGGL(k_gemm_mfma, dim3(bG2), blk, 0, stream, x,    W0, flags, 1, cnt, hA16, NNODES);
        hipLaunchKernelGGL(k_gather,    dim3(bGT), blk, 0, stream, cnt, ecol, hA16, b0, flags, (const int*)nullptr, hB16);
        hipLaunchKernelGGL(k_gemm_mfma, dim3(bG2), blk, 0, stream, hB16, W1, flags, 2, cnt, hA16, NNODES);
        hipLaunchKernelGGL(k_gather,    dim3(bGT), blk, 0, stream, cnt, ecol, hA16, b1, flags, (const int*)nullptr, hB16);
        hipLaunchKernelGGL(k_gemm_mfma, dim3(bG2), blk, 0, stream, hB16, W2, flags, 2, cnt, hA16, NNODES);
        hipLaunchKernelGGL(k_gather,    dim3(bGT), blk, 0, stream, cnt, ecol, hA16, b2, flags, (const int*)nullptr, hB16);

        // pool: 2-stage reduce (bounds computed in k_part1)
        hipLaunchKernelGGL(k_pool_part, dim3(NGRAPH * 4), blk, 0, stream, hB16, bounds, part);
        hipLaunchKernelGGL(k_pool_final, dim3(32), blk, 0, stream, part, bounds, flags, d_out);
    } else {
        // fallback: round-3 proven atomic path (fp32 everywhere)
        hipLaunchKernelGGL(k_detect, dim3(1), blk, 0, stream,
                           (const unsigned int*)x, (const unsigned int*)ei, flags);
        hipLaunchKernelGGL(k_deg_init, dim3(bN), blk, 0, stream, dinv);
        hipLaunchKernelGGL(k_deg_edges, dim3(bE), blk, 0, stream, ei, flags, dinv);
        hipLaunchKernelGGL(k_rsqrt, dim3(bN), blk, 0, stream, dinv);

        hipLaunchKernelGGL(k_gemm, dim3(bG), blk, 0, stream, x, W0, flags, 1, hA, NNODES);
        hipLaunchKernelGGL(k_selfloop, dim3(bNF), blk, 0, stream, hA, dinv, hB);
        hipLaunchKernelGGL(k_scatter, dim3(bEF), blk, 0, stream, ei, flags, dinv, hA, hB);
        hipLaunchKernelGGL(k_bias_relu, dim3(bNF), blk, 0, stream, hB, b0, flags);

        hipLaunchKernelGGL(k_gemm, dim3(bG), blk, 0, stream, hB, W1, flags, 0, hA, NNODES);
        hipLaunchKernelGGL(k_selfloop, dim3(bNF), blk, 0, stream, hA, dinv, hB);
        hipLaunchKernelGGL(k_scatter, dim3(bEF), blk, 0, stream, ei, flags, dinv, hA, hB);
        hipLaunchKernelGGL(k_bias_relu, dim3(bNF), blk, 0, stream, hB, b1, flags);

        hipLaunchKernelGGL(k_gemm, dim3(bG), blk, 0, stream, hB, W2, flags, 0, hA, NNODES);
        hipLaunchKernelGGL(k_selfloop, dim3(bNF), blk, 0, stream, hA, dinv, hB);
        hipLaunchKernelGGL(k_scatter, dim3(bEF), blk, 0, stream, ei, flags, dinv, hA, hB);
        hipLaunchKernelGGL(k_bias_relu, dim3(bNF), blk, 0, stream, hB, b2, flags);

        hipLaunchKernelGGL(k_bounds, dim3(1), dim3(128), 0, stream, bat, flags, bounds);
        hipLaunchKernelGGL(k_pool2, dim3(NGRAPH), dim3(1024), 0, stream, hB, bounds, flags, d_out);
    }
}

// Round 8
// 304.923 us; speedup vs baseline: 1.1198x; 1.0181x over previous
//
#include <hip/hip_runtime.h>
#include <hip/hip_bf16.h>

#define NNODES 50000
#define NEDGES 800000
#define HIDDIM 128
#define NGRAPH 64
#define BUCKET 64   // fixed CSR bucket capacity (mean deg 16, P(deg>=64)~2e-18)
#define NRANGE 196  // destination ranges of 256 nodes (r = d>>8)
#define RCAP 6144   // per-range segment capacity (mean 4081, +32 sigma)

typedef __attribute__((ext_vector_type(8))) short short8;
typedef __attribute__((ext_vector_type(4))) float floatx4;
typedef __attribute__((ext_vector_type(4))) unsigned int uintx4;

__device__ __forceinline__ float bfbits2f(unsigned short u) {
    return __uint_as_float(((unsigned int)u) << 16);
}
__device__ __forceinline__ unsigned short f2bfbits(float v) {
    __hip_bfloat16 h = __float2bfloat16(v);
    return __builtin_bit_cast(unsigned short, h);
}
__device__ __forceinline__ float bflo(unsigned int w) { return __uint_as_float(w << 16); }
__device__ __forceinline__ float bfhi(unsigned int w) { return __uint_as_float(w & 0xffff0000u); }

__device__ __forceinline__ void acc8w(float* __restrict__ a, uint4 r, float wt) {
    a[0] = fmaf(wt, bflo(r.x), a[0]); a[1] = fmaf(wt, bfhi(r.x), a[1]);
    a[2] = fmaf(wt, bflo(r.y), a[2]); a[3] = fmaf(wt, bfhi(r.y), a[3]);
    a[4] = fmaf(wt, bflo(r.z), a[4]); a[5] = fmaf(wt, bfhi(r.z), a[5]);
    a[6] = fmaf(wt, bflo(r.w), a[6]); a[7] = fmaf(wt, bfhi(r.w), a[7]);
}
__device__ __forceinline__ void acc8p(float* __restrict__ a, uint4 r) {
    a[0] += bflo(r.x); a[1] += bfhi(r.x);
    a[2] += bflo(r.y); a[3] += bfhi(r.y);
    a[4] += bflo(r.z); a[5] += bfhi(r.z);
    a[6] += bflo(r.w); a[7] += bfhi(r.w);
}

__device__ __forceinline__ int ld_idx(const int* __restrict__ p, int j, int wide) {
    return wide ? p[2 * j] : p[j];
}

// ---------------- shared GEMM pieces ----------------
// W staged to LDS: Wl[(kb*128 + n)*8 + kj] (m120-verified B-fragment layout).
__device__ __forceinline__ void stage_W(unsigned short* __restrict__ Wl,
                                        const void* __restrict__ W, int F, int tid) {
    if (F) {
        const ushort4* __restrict__ Wg = (const ushort4*)W;
#pragma unroll
        for (int it = 0; it < 16; ++it) {
            int idx = it * 256 + tid;
            int k = idx >> 5, n = (idx & 31) * 4;
            ushort4 wv = Wg[idx];
            unsigned short* dst = &Wl[(((k >> 3) * 128) + n) * 8 + (k & 7)];
            dst[0] = wv.x; dst[8] = wv.y; dst[16] = wv.z; dst[24] = wv.w;
        }
    } else {
        const float4* __restrict__ Wg = (const float4*)W;
#pragma unroll
        for (int it = 0; it < 16; ++it) {
            int idx = it * 256 + tid;
            int k = idx >> 5, n = (idx & 31) * 4;
            float4 wv = Wg[idx];
            unsigned short* dst = &Wl[(((k >> 3) * 128) + n) * 8 + (k & 7)];
            dst[0] = f2bfbits(wv.x); dst[8]  = f2bfbits(wv.y);
            dst[16] = f2bfbits(wv.z); dst[24] = f2bfbits(wv.w);
        }
    }
}

// 64-row GEMM body; A-fragments loaded DIRECTLY global->reg (16B per lane per kb:
// lane(q,c) reads A[row0+wave*16+c][(k0*4+q)*8 .. +8) — no A-LDS staging needed).
// Call after stage_W + __syncthreads.
__device__ __forceinline__ void gemm64_mfma(const unsigned short* __restrict__ Wl,
                                            const void* __restrict__ A, int abf,
                                            const int* __restrict__ degcnt,
                                            unsigned short* __restrict__ out,
                                            int M, int row0, int tid) {
    const int lane = tid & 63;
    const int wave = tid >> 6;
    const int q = lane >> 4;
    const int c = lane & 15;
    const int gra = row0 + wave * 16 + c;   // A-fragment source row for this lane
    short8 af[4];
    if (gra < M) {
        if (abf) {
            const unsigned short* ap = (const unsigned short*)A + (size_t)gra * 128 + q * 8;
#pragma unroll
            for (int k0 = 0; k0 < 4; ++k0)
                af[k0] = *reinterpret_cast<const short8*>(ap + k0 * 32);
        } else {
            const float* ap = (const float*)A + (size_t)gra * 128 + q * 8;
#pragma unroll
            for (int k0 = 0; k0 < 4; ++k0) {
                float4 f0 = *reinterpret_cast<const float4*>(ap + k0 * 32);
                float4 f1 = *reinterpret_cast<const float4*>(ap + k0 * 32 + 4);
                short8 v;
                v[0] = (short)f2bfbits(f0.x); v[1] = (short)f2bfbits(f0.y);
                v[2] = (short)f2bfbits(f0.z); v[3] = (short)f2bfbits(f0.w);
                v[4] = (short)f2bfbits(f1.x); v[5] = (short)f2bfbits(f1.y);
                v[6] = (short)f2bfbits(f1.z); v[7] = (short)f2bfbits(f1.w);
                af[k0] = v;
            }
        }
    } else {
#pragma unroll
        for (int k0 = 0; k0 < 4; ++k0) {
#pragma unroll
            for (int i = 0; i < 8; ++i) af[k0][i] = 0;
        }
    }
    floatx4 acc[8] = {};
#pragma unroll
    for (int k0 = 0; k0 < 4; ++k0) {
        int kb = k0 * 4 + q;
#pragma unroll
        for (int t = 0; t < 8; ++t) {
            short8 bfrag = *reinterpret_cast<const short8*>(&Wl[(kb * 128 + t * 16 + c) * 8]);
            acc[t] = __builtin_amdgcn_mfma_f32_16x16x32_bf16(af[k0], bfrag, acc[t], 0, 0, 0);
        }
    }
#pragma unroll
    for (int i = 0; i < 4; ++i) {
        int gr = row0 + wave * 16 + q * 4 + i;
        if (gr < M) {
            float s = degcnt ? rsqrtf((float)degcnt[gr] + 1.0f) : 1.0f;
#pragma unroll
            for (int t = 0; t < 8; ++t) {
                out[(size_t)gr * 128 + t * 16 + c] = f2bfbits(acc[t][i] * s);
            }
        }
    }
}

// ---------------- runtime dtype detection ----------------
// flags[0]=1: floats stored bf16; 0: fp32.  flags[1]=1: indices int64; 0: int32.
__global__ void k_detect(const unsigned int* __restrict__ xw,
                         const unsigned int* __restrict__ eiw,
                         int* __restrict__ flags) {
    __shared__ int sh_hit, sh_zero;
    int t = threadIdx.x;
    if (t == 0) { sh_hit = 0; sh_zero = 0; }
    __syncthreads();
    if (t < 128) {
        unsigned int w = xw[t * 97 + 5];
        int e = (int)((w >> 7) & 0xFF);
        if (e >= 110 && e <= 140) atomicAdd(&sh_hit, 1);
        if (eiw[1001 + 2 * t] == 0) atomicAdd(&sh_zero, 1);
    }
    __syncthreads();
    if (t == 0) {
        flags[0] = (sh_hit >= 64) ? 1 : 0;
        flags[1] = (sh_zero >= 120) ? 1 : 0;
    }
}

// CSR-path init: detect + zero rangecnt (196 ints). Single block.
__global__ void k_init(const unsigned int* __restrict__ xw,
                       const unsigned int* __restrict__ eiw,
                       int* __restrict__ flags, int* __restrict__ rangecnt) {
    __shared__ int sh_hit, sh_zero;
    int t = threadIdx.x;
    if (t < NRANGE) rangecnt[t] = 0;
    if (t == 0) { sh_hit = 0; sh_zero = 0; }
    __syncthreads();
    if (t < 128) {
        unsigned int w = xw[t * 97 + 5];
        int e = (int)((w >> 7) & 0xFF);
        if (e >= 110 && e <= 140) atomicAdd(&sh_hit, 1);
        if (eiw[1001 + 2 * t] == 0) atomicAdd(&sh_zero, 1);
    }
    __syncthreads();
    if (t == 0) {
        flags[0] = (sh_hit >= 64) ? 1 : 0;
        flags[1] = (sh_zero >= 120) ? 1 : 0;
    }
}

// ---------------- MERGED: radix part1 (0..390) + bounds (391) + gemm0 (392+) -----
// part1 is coalesced & low-BW after round-7 (no scattered-write pipe to share),
// so gemm0 (MFMA-bound, depends only on x,W0 once unscaled) rides alongside.
// 32KB shared union: part1's bins+staging (12KB) alias gemm's Wl (32KB).
__global__ __launch_bounds__(256) void k_p1g0(const int* __restrict__ ei,
                                              const int* __restrict__ bat,
                                              const int* __restrict__ flags,
                                              int* __restrict__ rangecnt,
                                              unsigned int* __restrict__ pairs,
                                              int* __restrict__ bounds,
                                              const void* __restrict__ A,
                                              const void* __restrict__ W,
                                              unsigned short* __restrict__ out,
                                              int M) {
    __shared__ __align__(16) unsigned int shm[8192];  // 32 KB union
    const int tid = threadIdx.x;

    if (blockIdx.x >= 392) {  // ---- gemm0: out = A @ W0 (bf16, UNSCALED) ----
        unsigned short* Wl = (unsigned short*)shm;
        const int F = flags[0];
        stage_W(Wl, W, F, tid);
        __syncthreads();
        gemm64_mfma(Wl, A, F, nullptr, out, M, (blockIdx.x - 392) * 64, tid);
        return;
    }
    if (blockIdx.x == 391) {  // ---- pool bounds (binary search per graph) ----
        int g = tid;
        if (g > NGRAPH) return;
        int wide = flags[1];
        int lo = 0, hi = NNODES;
        while (lo < hi) {
            int mid = (lo + hi) >> 1;
            if (ld_idx(bat, mid, wide) < g) lo = mid + 1; else hi = mid;
        }
        bounds[g] = lo;
        return;
    }
    // ---- part1: 2048 edges/block, bin by r=d>>8, one global atomic/(block,range),
    // bin-ordered contiguous writes (round-7 proven) ----
    int* lcnt   = (int*)shm;          // [196] (256-slot stride)
    int* lbase  = (int*)shm + 256;
    int* lpos   = (int*)shm + 512;
    int* gchunk = (int*)shm + 768;
    unsigned int* stg = shm + 1024;   // [2048]
    if (tid < NRANGE) lcnt[tid] = 0;
    __syncthreads();

    int T = blockIdx.x * 256 + tid;
    int e0 = T * 8;
    const bool live = (e0 < NEDGES);  // NEDGES%8==0: live threads own full groups
    int s[8], d[8];
    if (live) {
        int wide = flags[1];
        if (wide) {
            const int4* __restrict__ sp = (const int4*)ei;
            const int4* __restrict__ dp = (const int4*)(ei + 2 * NEDGES);
#pragma unroll
            for (int q = 0; q < 4; ++q) {
                int4 sv = sp[T * 4 + q]; s[2 * q] = sv.x; s[2 * q + 1] = sv.z;
                int4 dv = dp[T * 4 + q]; d[2 * q] = dv.x; d[2 * q + 1] = dv.z;
            }
        } else {
            const int4* __restrict__ sp = (const int4*)ei;
            const int4* __restrict__ dp = (const int4*)(ei + NEDGES);
#pragma unroll
            for (int q = 0; q < 2; ++q) {
                int4 sv = sp[T * 2 + q];
                s[4 * q] = sv.x; s[4 * q + 1] = sv.y; s[4 * q + 2] = sv.z; s[4 * q + 3] = sv.w;
                int4 dv = dp[T * 2 + q];
                d[4 * q] = dv.x; d[4 * q + 1] = dv.y; d[4 * q + 2] = dv.z; d[4 * q + 3] = dv.w;
            }
        }
#pragma unroll
        for (int q = 0; q < 8; ++q) atomicAdd(&lcnt[d[q] >> 8], 1);
    }
    __syncthreads();
    if (tid == 0) {  // serial prefix over 196 bins (hidden by cross-block overlap)
        int run = 0;
        for (int i = 0; i < NRANGE; ++i) {
            lbase[i] = run; lpos[i] = run; run += lcnt[i];
        }
    }
    __syncthreads();
    if (tid < NRANGE) {
        int c = lcnt[tid];
        gchunk[tid] = (c > 0) ? atomicAdd(&rangecnt[tid], c) : 0;
    }
    __syncthreads();
    if (live) {
#pragma unroll
        for (int q = 0; q < 8; ++q) {
            int r = d[q] >> 8;
            int p = atomicAdd(&lpos[r], 1);
            stg[p] = ((unsigned)r << 24) | (((unsigned)d[q] & 255u) << 16) |
                     ((unsigned)s[q] & 0xffffu);
        }
    }
    __syncthreads();
    const int total = lbase[NRANGE - 1] + lcnt[NRANGE - 1];
    for (int p = tid; p < total; p += 256) {
        unsigned w = stg[p];
        int r = (int)(w >> 24);
        int off = gchunk[r] + (p - lbase[r]);
        if (off < RCAP) pairs[(size_t)r * RCAP + off] = w;
    }
}

// ---------------- radix build phase 2: segment -> LDS buckets -> coalesced ecol ---
__global__ __launch_bounds__(256) void k_part2(const int* __restrict__ rangecnt,
                                               const unsigned int* __restrict__ pairs,
                                               unsigned short* __restrict__ ecol,
                                               int* __restrict__ cnt) {
    __shared__ __align__(16) unsigned short lb[256 * BUCKET];  // 32 KB
    __shared__ int lc[256];
    const int r = blockIdx.x;
    const int tid = threadIdx.x;
    lc[tid] = 0;
    __syncthreads();
    int n_r = rangecnt[r];
    if (n_r > RCAP) n_r = RCAP;
    for (int p = tid; p < n_r; p += 256) {
        unsigned w = pairs[(size_t)r * RCAP + p];
        int dlow = (int)((w >> 16) & 0xffu);
        int pos = atomicAdd(&lc[dlow], 1);
        if (pos < BUCKET) lb[dlow * BUCKET + pos] = (unsigned short)(w & 0xffffu);
    }
    __syncthreads();
    const int node0 = r * 256;
    int vn = NNODES - node0; if (vn > 256) vn = 256;  // last range: 80 valid nodes
    if (tid < vn) cnt[node0 + tid] = lc[tid];
    const uintx4* __restrict__ src = reinterpret_cast<const uintx4*>(lb);
    uintx4* __restrict__ dst = reinterpret_cast<uintx4*>(ecol + (size_t)node0 * BUCKET);
    const int nvec = vn * 8;  // 64 ushorts = 8 uint4 per node
    for (int i = tid; i < nvec; i += 256) dst[i] = src[i];
}

// ---------------- MFMA GEMM: out_bf16[M,128] = (A @ W) * rsqrt(cnt[m]+1) ----------
// a_mode: 0=fp32 A, 1=A follows flags[0], 2=A is bf16 bits. W-only LDS (32KB).
__global__ __launch_bounds__(256) void k_gemm_mfma(const void* __restrict__ A,
                                                   const void* __restrict__ W,
                                                   const int* __restrict__ flags,
                                                   int a_mode,
                                                   const int* __restrict__ degcnt,
                                                   unsigned short* __restrict__ out,
                                                   int M) {
    __shared__ __align__(16) unsigned short Wl[16 * 128 * 8];   // 32 KB
    const int tid = threadIdx.x;
    const int F = flags[0];
    const int abf = (a_mode == 2) ? 1 : (a_mode == 1 ? F : 0);
    stage_W(Wl, W, F, tid);
    __syncthreads();
    gemm64_mfma(Wl, A, abf, degcnt, out, M, blockIdx.x * 64, tid);
}

// ---------------- fused gather (bf16 in/out): row-sum + scale + bias + relu --------
// 16 lanes/node, 8-wide MLP deg loop (round-6 confirmed: latency-bound, ~34us).
// scl==null: rows pre-scaled by dinv. scl!=null: rows unscaled, weight by
// rsqrt(scl[src]+1) (layer 1, fed by unscaled merged gemm0).
__global__ __launch_bounds__(256) void k_gather(const int* __restrict__ cnt,
                                                const unsigned short* __restrict__ ecol,
                                                const unsigned short* __restrict__ tmp16,
                                                const void* __restrict__ bias,
                                                const int* __restrict__ flags,
                                                const int* __restrict__ scl,
                                                unsigned short* __restrict__ outh16) {
    int t = blockIdx.x * 256 + threadIdx.x;
    int n = t >> 4;
    if (n >= NNODES) return;
    int j = t & 15;  // 16B chunk = bf16 columns [j*8, j*8+8)
    int degf = cnt[n];
    float dn = rsqrtf((float)degf + 1.0f);
    int deg = degf > BUCKET ? BUCKET : degf;
    const unsigned short* __restrict__ bk = &ecol[(size_t)n * BUCKET];
    const uint4* __restrict__ base = reinterpret_cast<const uint4*>(tmp16);
    float a[8];
    {
        uint4 u = base[(size_t)n * 16 + j];  // self-loop term
        float w0 = scl ? dn : 1.0f;
        a[0] = w0 * bflo(u.x); a[1] = w0 * bfhi(u.x);
        a[2] = w0 * bflo(u.y); a[3] = w0 * bfhi(u.y);
        a[4] = w0 * bflo(u.z); a[5] = w0 * bfhi(u.z);
        a[6] = w0 * bflo(u.w); a[7] = w0 * bfhi(u.w);
    }
    int k = 0;
    if (scl) {
        for (; k + 7 < deg; k += 8) {
            uint4 bw = *reinterpret_cast<const uint4*>(&bk[k]);
            int s0 = bw.x & 0xffff, s1 = bw.x >> 16;
            int s2 = bw.y & 0xffff, s3 = bw.y >> 16;
            int s4 = bw.z & 0xffff, s5 = bw.z >> 16;
            int s6 = bw.w & 0xffff, s7 = bw.w >> 16;
            uint4 r0 = base[(size_t)s0 * 16 + j];
            uint4 r1 = base[(size_t)s1 * 16 + j];
            uint4 r2 = base[(size_t)s2 * 16 + j];
            uint4 r3 = base[(size_t)s3 * 16 + j];
            uint4 r4 = base[(size_t)s4 * 16 + j];
            uint4 r5 = base[(size_t)s5 * 16 + j];
            uint4 r6 = base[(size_t)s6 * 16 + j];
            uint4 r7 = base[(size_t)s7 * 16 + j];
            acc8w(a, r0, rsqrtf((float)scl[s0] + 1.0f));
            acc8w(a, r1, rsqrtf((float)scl[s1] + 1.0f));
            acc8w(a, r2, rsqrtf((float)scl[s2] + 1.0f));
            acc8w(a, r3, rsqrtf((float)scl[s3] + 1.0f));
            acc8w(a, r4, rsqrtf((float)scl[s4] + 1.0f));
            acc8w(a, r5, rsqrtf((float)scl[s5] + 1.0f));
            acc8w(a, r6, rsqrtf((float)scl[s6] + 1.0f));
            acc8w(a, r7, rsqrtf((float)scl[s7] + 1.0f));
        }
        for (; k < deg; ++k) {
            int s0 = bk[k];
            uint4 r0 = base[(size_t)s0 * 16 + j];
            acc8w(a, r0, rsqrtf((float)scl[s0] + 1.0f));
        }
    } else {
        for (; k + 7 < deg; k += 8) {
            uint4 bw = *reinterpret_cast<const uint4*>(&bk[k]);
            int s0 = bw.x & 0xffff, s1 = bw.x >> 16;
            int s2 = bw.y & 0xffff, s3 = bw.y >> 16;
            int s4 = bw.z & 0xffff, s5 = bw.z >> 16;
            int s6 = bw.w & 0xffff, s7 = bw.w >> 16;
            uint4 r0 = base[(size_t)s0 * 16 + j];
            uint4 r1 = base[(size_t)s1 * 16 + j];
            uint4 r2 = base[(size_t)s2 * 16 + j];
            uint4 r3 = base[(size_t)s3 * 16 + j];
            uint4 r4 = base[(size_t)s4 * 16 + j];
            uint4 r5 = base[(size_t)s5 * 16 + j];
            uint4 r6 = base[(size_t)s6 * 16 + j];
            uint4 r7 = base[(size_t)s7 * 16 + j];
            acc8p(a, r0); acc8p(a, r1); acc8p(a, r2); acc8p(a, r3);
            acc8p(a, r4); acc8p(a, r5); acc8p(a, r6); acc8p(a, r7);
        }
        for (; k + 3 < deg; k += 4) {
            uint2 bw = *reinterpret_cast<const uint2*>(&bk[k]);
            int s0 = bw.x & 0xffff, s1 = bw.x >> 16;
            int s2 = bw.y & 0xffff, s3 = bw.y >> 16;
            uint4 r0 = base[(size_t)s0 * 16 + j];
            uint4 r1 = base[(size_t)s1 * 16 + j];
            uint4 r2 = base[(size_t)s2 * 16 + j];
            uint4 r3 = base[(size_t)s3 * 16 + j];
            acc8p(a, r0); acc8p(a, r1); acc8p(a, r2); acc8p(a, r3);
        }
        for (; k < deg; ++k) {
            uint4 r0 = base[(size_t)bk[k] * 16 + j];
            acc8p(a, r0);
        }
    }
    float b[8];
    if (flags[0]) {
        uint4 bb = ((const uint4*)bias)[j];
        b[0] = bflo(bb.x); b[1] = bfhi(bb.x);
        b[2] = bflo(bb.y); b[3] = bfhi(bb.y);
        b[4] = bflo(bb.z); b[5] = bfhi(bb.z);
        b[6] = bflo(bb.w); b[7] = bfhi(bb.w);
    } else {
        float4 f0 = ((const float4*)bias)[2 * j];
        float4 f1 = ((const float4*)bias)[2 * j + 1];
        b[0] = f0.x; b[1] = f0.y; b[2] = f0.z; b[3] = f0.w;
        b[4] = f1.x; b[5] = f1.y; b[6] = f1.z; b[7] = f1.w;
    }
    uintx4 ov;
#pragma unroll
    for (int i2 = 0; i2 < 4; ++i2) {
        float r0 = fmaxf(a[2 * i2]     * dn + b[2 * i2],     0.0f);
        float r1 = fmaxf(a[2 * i2 + 1] * dn + b[2 * i2 + 1], 0.0f);
        ov[i2] = (unsigned int)f2bfbits(r0) | ((unsigned int)f2bfbits(r1) << 16);
    }
    __builtin_nontemporal_store(ov,
        reinterpret_cast<uintx4*>(outh16 + (size_t)n * 128 + j * 8));
}

// ---------------- fallback (round-3 proven) atomic-scatter path ----------------
__global__ __launch_bounds__(256) void k_gemm(const void* __restrict__ A,
                                              const void* __restrict__ W,
                                              const int* __restrict__ flags,
                                              int a_uses_flag,
                                              float* __restrict__ out, int M) {
    __shared__ __align__(16) float Al[32 * 128];
    const int tid = threadIdx.x;
    const int F = flags[0];
    const int afmt = a_uses_flag ? F : 0;
    const int row0 = blockIdx.x * 32;
#pragma unroll
    for (int j = 0; j < 16; ++j) {
        int idx = j * 256 + tid;
        int r = idx >> 7, k = idx & 127;
        int gr = row0 + r;
        float v = 0.0f;
        if (gr < M) {
            size_t off = (size_t)gr * 128 + k;
            v = afmt ? bfbits2f(((const unsigned short*)A)[off])
                     : ((const float*)A)[off];
        }
        Al[idx] = v;
    }
    __syncthreads();
    const int tx = tid & 31, ty = tid >> 5;
    const int c0 = tx * 4;
    float acc[4][4] = {};
    if (F) {
        const ushort4* __restrict__ Wg = (const ushort4*)W;
#pragma unroll 4
        for (int k = 0; k < 128; ++k) {
            ushort4 wv = Wg[k * 32 + tx];
            float w0 = bfbits2f(wv.x), w1 = bfbits2f(wv.y);
            float w2 = bfbits2f(wv.z), w3 = bfbits2f(wv.w);
#pragma unroll
            for (int i = 0; i < 4; ++i) {
                float a = Al[(ty + i * 8) * 128 + k];
                acc[i][0] = fmaf(a, w0, acc[i][0]);
                acc[i][1] = fmaf(a, w1, acc[i][1]);
                acc[i][2] = fmaf(a, w2, acc[i][2]);
                acc[i][3] = fmaf(a, w3, acc[i][3]);
            }
        }
    } else {
        const float4* __restrict__ Wg = (const float4*)W;
#pragma unroll 4
        for (int k = 0; k < 128; ++k) {
            float4 wv = Wg[k * 32 + tx];
#pragma unroll
            for (int i = 0; i < 4; ++i) {
                float a = Al[(ty + i * 8) * 128 + k];
                acc[i][0] = fmaf(a, wv.x, acc[i][0]);
                acc[i][1] = fmaf(a, wv.y, acc[i][1]);
                acc[i][2] = fmaf(a, wv.z, acc[i][2]);
                acc[i][3] = fmaf(a, wv.w, acc[i][3]);
            }
        }
    }
#pragma unroll
    for (int i = 0; i < 4; ++i) {
        int gr = row0 + ty + i * 8;
        if (gr < M) {
            *reinterpret_cast<float4*>(&out[(size_t)gr * 128 + c0]) =
                make_float4(acc[i][0], acc[i][1], acc[i][2], acc[i][3]);
        }
    }
}
__global__ void k_deg_init(float* __restrict__ deg) {
    int i = blockIdx.x * 256 + threadIdx.x;
    if (i < NNODES) deg[i] = 1.0f;
}
__global__ void k_deg_edges(const int* __restrict__ ei, const int* __restrict__ flags,
                            float* __restrict__ deg) {
    int e = blockIdx.x * 256 + threadIdx.x;
    if (e < NEDGES) unsafeAtomicAdd(&deg[ld_idx(ei, NEDGES + e, flags[1])], 1.0f);
}
__global__ void k_rsqrt(float* __restrict__ deg) {
    int i = blockIdx.x * 256 + threadIdx.x;
    if (i < NNODES) deg[i] = 1.0f / sqrtf(deg[i]);
}
__global__ void k_selfloop(const float* __restrict__ tmp, const float* __restrict__ dinv,
                           float* __restrict__ agg) {
    int t = blockIdx.x * 256 + threadIdx.x;
    if (t >= NNODES * 32) return;
    int n = t >> 5, j = t & 31;
    float s = dinv[n]; s = s * s;
    float4 v = *reinterpret_cast<const float4*>(&tmp[(size_t)n * 128 + j * 4]);
    v.x *= s; v.y *= s; v.z *= s; v.w *= s;
    *reinterpret_cast<float4*>(&agg[(size_t)n * 128 + j * 4]) = v;
}
__global__ __launch_bounds__(256) void k_scatter(const int* __restrict__ ei,
                                                 const int* __restrict__ flags,
                                                 const float* __restrict__ dinv,
                                                 const float* __restrict__ tmp,
                                                 float* __restrict__ agg) {
    int t = blockIdx.x * 256 + threadIdx.x;
    int e = t >> 5;
    if (e >= NEDGES) return;
    int j = t & 31;
    int wide = flags[1];
    int s = ld_idx(ei, e, wide);
    int d = ld_idx(ei, NEDGES + e, wide);
    float w = dinv[s] * dinv[d];
    const float4 v = *reinterpret_cast<const float4*>(&tmp[(size_t)s * 128 + j * 4]);
    float* p = &agg[(size_t)d * 128 + j * 4];
    unsafeAtomicAdd(p + 0, v.x * w);
    unsafeAtomicAdd(p + 1, v.y * w);
    unsafeAtomicAdd(p + 2, v.z * w);
    unsafeAtomicAdd(p + 3, v.w * w);
}
__global__ void k_bias_relu(float* __restrict__ h, const void* __restrict__ b,
                            const int* __restrict__ flags) {
    int t = blockIdx.x * 256 + threadIdx.x;
    if (t >= NNODES * 32) return;
    int j = t & 31;
    float b0, b1, b2, b3;
    if (flags[0]) {
        const unsigned short* bb = (const unsigned short*)b;
        b0 = bfbits2f(bb[j * 4 + 0]); b1 = bfbits2f(bb[j * 4 + 1]);
        b2 = bfbits2f(bb[j * 4 + 2]); b3 = bfbits2f(bb[j * 4 + 3]);
    } else {
        const float* bb = (const float*)b;
        b0 = bb[j * 4 + 0]; b1 = bb[j * 4 + 1]; b2 = bb[j * 4 + 2]; b3 = bb[j * 4 + 3];
    }
    float4 v = *reinterpret_cast<float4*>(&h[(size_t)t * 4]);
    v.x = fmaxf(v.x + b0, 0.0f);
    v.y = fmaxf(v.y + b1, 0.0f);
    v.z = fmaxf(v.z + b2, 0.0f);
    v.w = fmaxf(v.w + b3, 0.0f);
    *reinterpret_cast<float4*>(&h[(size_t)t * 4]) = v;
}

// ---------------- pooling ----------------
__global__ void k_bounds(const int* __restrict__ batch, const int* __restrict__ flags,
                         int* __restrict__ bounds) {
    int g = threadIdx.x;
    if (g > NGRAPH) return;
    int wide = flags[1];
    int lo = 0, hi = NNODES;
    while (lo < hi) {
        int mid = (lo + hi) >> 1;
        if (ld_idx(batch, mid, wide) < g) lo = mid + 1; else hi = mid;
    }
    bounds[g] = lo;
}

// stage 1: 256 blocks = 4 segments x 64 graphs; bf16 h input; fp32 partials.
__global__ __launch_bounds__(256) void k_pool_part(const unsigned short* __restrict__ h16,
                                                   const int* __restrict__ bounds,
                                                   float* __restrict__ part) {
    __shared__ float sh[256 * 4];
    int g = blockIdx.x >> 2, seg = blockIdx.x & 3;
    int t = threadIdx.x;
    int c4 = t & 31, sub = t >> 5;  // sub in [0,8)
    int beg = bounds[g], end = bounds[g + 1];
    const ushort4* __restrict__ base = (const ushort4*)h16;
    float ax = 0, ay = 0, az = 0, aw = 0;
    for (int r = beg + seg * 8 + sub; r < end; r += 32) {
        ushort4 u = base[(size_t)r * 32 + c4];
        ax += bfbits2f(u.x); ay += bfbits2f(u.y);
        az += bfbits2f(u.z); aw += bfbits2f(u.w);
    }
    sh[t * 4 + 0] = ax; sh[t * 4 + 1] = ay; sh[t * 4 + 2] = az; sh[t * 4 + 3] = aw;
    __syncthreads();
    if (t < 32) {
        float4 r = make_float4(0, 0, 0, 0);
#pragma unroll
        for (int s = 0; s < 8; ++s) {
            r.x += sh[(s * 32 + t) * 4 + 0];
            r.y += sh[(s * 32 + t) * 4 + 1];
            r.z += sh[(s * 32 + t) * 4 + 2];
            r.w += sh[(s * 32 + t) * 4 + 3];
        }
        *reinterpret_cast<float4*>(&part[((size_t)(g * 4 + seg)) * 128 + t * 4]) = r;
    }
}

__global__ void k_pool_final(const float* __restrict__ part, const int* __restrict__ bounds,
                             const int* __restrict__ flags, void* __restrict__ out) {
    int i = blockIdx.x * 256 + threadIdx.x;
    if (i >= NGRAPH * 128) return;
    int g = i >> 7, col = i & 127;
    float s = part[(g * 4 + 0) * 128 + col] + part[(g * 4 + 1) * 128 + col] +
              part[(g * 4 + 2) * 128 + col] + part[(g * 4 + 3) * 128 + col];
    float c = (float)(bounds[g + 1] - bounds[g]);
    float r = s / fmaxf(c, 1.0f);
    if (flags[0]) ((__hip_bfloat16*)out)[i] = __float2bfloat16(r);
    else          ((float*)out)[i] = r;
}

// fallback pool (fp32 h)
__global__ __launch_bounds__(1024) void k_pool2(const float* __restrict__ h,
                                                const int* __restrict__ bounds,
                                                const int* __restrict__ flags,
                                                void* __restrict__ out) {
    __shared__ float sh[1024];
    int g = blockIdx.x;
    int t = threadIdx.x;
    int beg = bounds[g], end = bounds[g + 1];
    int col = t & 127, seg = t >> 7;
    float acc = 0.0f;
    for (int r = beg + seg; r < end; r += 8)
        acc += h[(size_t)r * 128 + col];
    sh[t] = acc;
    __syncthreads();
    if (t < 128) {
        float total = 0.0f;
#pragma unroll
        for (int i = 0; i < 8; ++i) total += sh[t + 128 * i];
        float c = (float)(end - beg);
        float r = total / fmaxf(c, 1.0f);
        if (flags[0]) ((__hip_bfloat16*)out)[g * 128 + t] = __float2bfloat16(r);
        else          ((float*)out)[g * 128 + t] = r;
    }
}

extern "C" void kernel_launch(void* const* d_in, const int* in_sizes, int n_in,
                              void* d_out, int out_size, void* d_ws, size_t ws_size,
                              hipStream_t stream) {
    const void* x  = d_in[0];
    const int* ei  = (const int*)d_in[1];
    const int* bat = (const int*)d_in[2];
    const void* W0 = d_in[3];
    const void* b0 = d_in[4];
    const void* W1 = d_in[5];
    const void* b1 = d_in[6];
    const void* W2 = d_in[7];
    const void* b2 = d_in[8];

    // Workspace: flags | dinv | hA-region(6.4M f) | hB-region(6.4M f) | bounds | cnt | part
    // CSR overlays: hA16 = first half of hA; ecol (6.4MB) = second half of hA;
    // hB16 = first half of hB; pairs (4.8MB, radix scratch) = start of hB (dead
    // before the first gather writes hB16); rangecnt = dinv slot (ints).
    float* ws = (float*)d_ws;
    size_t off = 0;
    int*   flags  = (int*)ws;           off += 16;
    float* dinv   = ws + off;           off += 50176;
    float* hA     = ws + off;           off += (size_t)NNODES * 128;
    float* hB     = ws + off;           off += (size_t)NNODES * 128;
    int*   bounds = (int*)(ws + off);   off += 80;
    int*   cnt    = (int*)(ws + off);   off += 50304;
    float* part   = ws + off;           off += NGRAPH * 4 * 128 + 64;
    const size_t needed = off * 4;
    unsigned short* hA16 = (unsigned short*)hA;
    unsigned short* hB16 = (unsigned short*)hB;
    unsigned short* ecol = (unsigned short*)(hA + (size_t)NNODES * 64);  // 3.2M ushorts
    int* rangecnt = (int*)dinv;
    unsigned int* pairs = (unsigned int*)hB;   // 196*6144*4B = 4.8MB

    const int bN  = (NNODES + 255) / 256;       // 196
    const int bE  = (NEDGES + 255) / 256;       // 3125
    const int bNF = (NNODES * 32) / 256;        // 6250
    const int bEF = (NEDGES * 32) / 256;        // 100000
    const int bP1 = (NEDGES + 2047) / 2048;     // 391 (part1 edge blocks)
    const int bGT = (NNODES * 16) / 256;        // 3125 (gather, 16 lanes/node)
    const int bG  = (NNODES + 31) / 32;         // 1563 (vector gemm)
    const int bG2 = (NNODES + 63) / 64;         // 782  (mfma gemm)
    dim3 blk(256);

    const bool use_csr = (ws_size >= needed);

    if (use_csr) {
        // init (detect + zero rangecnt) -> merged [part1 | bounds | gemm0-unscaled]
        hipLaunchKernelGGL(k_init, dim3(1), blk, 0, stream,
                           (const unsigned int*)x, (const unsigned int*)ei, flags, rangecnt);
        hipLaunchKernelGGL(k_p1g0, dim3(392 + bG2), blk, 0, stream,
                           ei, bat, flags, rangecnt, pairs, bounds, x, W0, hA16, NNODES);
        hipLaunchKernelGGL(k_part2, dim3(NRANGE), blk, 0, stream,
                           rangecnt, pairs, ecol, cnt);

        // layer 1: scl-gather (explicit per-neighbor dinv); layers 2,3: prescaled
        hipLaunchKernelGGL(k_gather,    dim3(bGT), blk, 0, stream, cnt, ecol, hA16, b0, flags, cnt, hB16);
        hipLaunchKernelGGL(k_gemm_mfma, dim3(bG2), blk, 0, stream, hB16, W1, flags, 2, cnt, hA16, NNODES);
        hipLaunchKernelGGL(k_gather,    dim3(bGT), blk, 0, stream, cnt, ecol, hA16, b1, flags, (const int*)nullptr, hB16);
        hipLaunchKernelGGL(k_gemm_mfma, dim3(bG2), blk, 0, stream, hB16, W2, flags, 2, cnt, hA16, NNODES);
        hipLaunchKernelGGL(k_gather,    dim3(bGT), blk, 0, stream, cnt, ecol, hA16, b2, flags, (const int*)nullptr, hB16);

        // pool: 2-stage reduce (bounds computed in k_p1g0)
        hipLaunchKernelGGL(k_pool_part, dim3(NGRAPH * 4), blk, 0, stream, hB16, bounds, part);
        hipLaunchKernelGGL(k_pool_final, dim3(32), blk, 0, stream, part, bounds, flags, d_out);
    } else {
        // fallback: round-3 proven atomic path (fp32 everywhere)
        hipLaunchKernelGGL(k_detect, dim3(1), blk, 0, stream,
                           (const unsigned int*)x, (const unsigned int*)ei, flags);
        hipLaunchKernelGGL(k_deg_init, dim3(bN), blk, 0, stream, dinv);
        hipLaunchKernelGGL(k_deg_edges, dim3(bE), blk, 0, stream, ei, flags, dinv);
        hipLaunchKernelGGL(k_rsqrt, dim3(bN), blk, 0, stream, dinv);

        hipLaunchKernelGGL(k_gemm, dim3(bG), blk, 0, stream, x, W0, flags, 1, hA, NNODES);
        hipLaunchKernelGGL(k_selfloop, dim3(bNF), blk, 0, stream, hA, dinv, hB);
        hipLaunchKernelGGL(k_scatter, dim3(bEF), blk, 0, stream, ei, flags, dinv, hA, hB);
        hipLaunchKernelGGL(k_bias_relu, dim3(bNF), blk, 0, stream, hB, b0, flags);

        hipLaunchKernelGGL(k_gemm, dim3(bG), blk, 0, stream, hB, W1, flags, 0, hA, NNODES);
        hipLaunchKernelGGL(k_selfloop, dim3(bNF), blk, 0, stream, hA, dinv, hB);
        hipLaunchKernelGGL(k_scatter, dim3(bEF), blk, 0, stream, ei, flags, dinv, hA, hB);
        hipLaunchKernelGGL(k_bias_relu, dim3(bNF), blk, 0, stream, hB, b1, flags);

        hipLaunchKernelGGL(k_gemm, dim3(bG), blk, 0, stream, hB, W2, flags, 0, hA, NNODES);
        hipLaunchKernelGGL(k_selfloop, dim3(bNF), blk, 0, stream, hA, dinv, hB);
        hipLaunchKernelGGL(k_scatter, dim3(bEF), blk, 0, stream, ei, flags, dinv, hA, hB);
        hipLaunchKernelGGL(k_bias_relu, dim3(bNF), blk, 0, stream, hB, b2, flags);

        hipLaunchKernelGGL(k_bounds, dim3(1), dim3(128), 0, stream, bat, flags, bounds);
        hipLaunchKernelGGL(k_pool2, dim3(NGRAPH), dim3(1024), 0, stream, hB, bounds, flags, d_out);
    }
}